// Round 23
// baseline (1392.069 us; speedup 1.0000x reference)
//
#include <hip/hip_runtime.h>
#include <hip/hip_bf16.h>
#include <math.h>

typedef __hip_bfloat16 bf16;
typedef __attribute__((ext_vector_type(8))) short short8;
typedef __attribute__((ext_vector_type(4))) float f32x4;

#define HIDD   768
#define SEQL   197
#define NPATCH 196
#define PATCHD 256
#define NHEADS 12
#define NBATCH 8
#define OUTDIM 1000
#define NBLOCKS 6
#define EPSV   1e-5f
#define HH     (NHEADS * HIDD)       /* 9216 */
#define M_ALL  (NBATCH * SEQL)       /* 1576 */
#define MPATCH (NBATCH * NPATCH)     /* 1568 */
#define PLD    256
#define KPV    224
#define KSPLIT 8

// ---------- helpers ----------
__device__ __forceinline__ unsigned short f2bf(float f) {
  union { bf16 h; unsigned short u; } cv; cv.h = __float2bfloat16(f); return cv.u;
}
__device__ __forceinline__ float bf2f(unsigned short u) {
  union { unsigned int i; float f; } w; w.i = ((unsigned int)u) << 16; return w.f;
}

typedef __attribute__((address_space(3))) unsigned int lds_uint;
typedef __attribute__((address_space(1))) const unsigned int g_uint;
__device__ __forceinline__ void gload16(const void* g, void* l) {
  __builtin_amdgcn_global_load_lds((g_uint*)g, (lds_uint*)l, 16, 0, 0);
}

// ---------- fp32 -> bf16 convert ----------
__global__ __launch_bounds__(256) void cvt_bf(const float4* __restrict__ src,
                                              ushort4* __restrict__ dst, int n4) {
  for (int i = blockIdx.x * 256 + threadIdx.x; i < n4; i += gridDim.x * 256) {
    float4 v = src[i];
    ushort4 o;
    o.x = f2bf(v.x); o.y = f2bf(v.y); o.z = f2bf(v.z); o.w = f2bf(v.w);
    dst[i] = o;
  }
}

// ---------- per-call: tiled fp32->bf16 per-head transpose  Dst[h][c][r] = S[h][r][c] ----------
__global__ __launch_bounds__(256) void wtrans(const float* __restrict__ S,
    unsigned short* __restrict__ Dst) {
  __shared__ unsigned short tile[64][72];
  const int h = blockIdx.z;
  const int c0 = blockIdx.x * 64, r0 = blockIdx.y * 64;
  const long long base = (long long)h * HIDD * HIDD;
  const int tr = threadIdx.x >> 2;
  const int tc = (threadIdx.x & 3) * 16;
#pragma unroll
  for (int j = 0; j < 4; ++j) {
    float4 v = *(const float4*)(S + base + (long long)(r0 + tr) * HIDD + c0 + tc + j * 4);
    tile[tr][tc + j * 4 + 0] = f2bf(v.x);
    tile[tr][tc + j * 4 + 1] = f2bf(v.y);
    tile[tr][tc + j * 4 + 2] = f2bf(v.z);
    tile[tr][tc + j * 4 + 3] = f2bf(v.w);
  }
  __syncthreads();
  const int er = threadIdx.x >> 2;
  const int ec = (threadIdx.x & 3) * 16;
  unsigned short tmp[16];
#pragma unroll
  for (int j = 0; j < 16; ++j) tmp[j] = tile[ec + j][er];
  unsigned short* drow = Dst + ((long long)h * HIDD + c0 + er) * HIDD + r0 + ec;
  *(int4*)drow = *(int4*)&tmp[0];
  *(int4*)(drow + 8) = *(int4*)&tmp[8];
}

// ---------- per-call: c[h][d'] = Wkt_bf[h][d'] . bq[h]  (wave per output) ----------
__global__ __launch_bounds__(256) void cvec2(const unsigned short* __restrict__ Wkt,
    const float* __restrict__ bq, float* __restrict__ c) {
  const int h = blockIdx.y;
  const int dp = blockIdx.x * 4 + (threadIdx.x >> 6);
  const int lane = threadIdx.x & 63;
  const unsigned short* row = Wkt + ((long long)h * HIDD + dp) * HIDD;
  const float* b = bq + h * HIDD;
  float s = 0.f;
  for (int e = lane * 4; e < HIDD; e += 256) {
    ushort4 w = *(const ushort4*)(row + e);
    s += bf2f(w.x) * b[e] + bf2f(w.y) * b[e + 1]
       + bf2f(w.z) * b[e + 2] + bf2f(w.w) * b[e + 3];
  }
  for (int o = 32; o; o >>= 1) s += __shfl_xor(s, o, 64);
  if (lane == 0) c[h * HIDD + dp] = s;
}

// ---------- one-time: beff[d] = bo[d] + Wo[d,:] . bv ----------
__global__ __launch_bounds__(256) void beff_k(const float* __restrict__ Wo,
    const float* __restrict__ bv, const float* __restrict__ bo,
    float* __restrict__ beff) {
  const int dout = blockIdx.x * 4 + (threadIdx.x >> 6);
  const int lane = threadIdx.x & 63;
  const float* row = Wo + (long long)dout * HH;
  float s = 0.f;
  for (int i = lane * 4; i < HH; i += 256) {
    float4 w = *(const float4*)(row + i);
    float4 b = *(const float4*)(bv + i);
    s += w.x * b.x + w.y * b.y + w.z * b.z + w.w * b.w;
  }
  for (int o = 32; o; o >>= 1) s += __shfl_xor(s, o, 64);
  if (lane == 0) beff[dout] = bo[dout] + s;
}

// ---------- per-iter: D[z][t] = c[h] . xnb[n*SEQL+t]  (wave per row) ----------
__global__ __launch_bounds__(256) void dcol(const unsigned short* __restrict__ Xn,
    const float* __restrict__ c, float* __restrict__ D) {
  const int z = blockIdx.x;
  const int n = z / NHEADS, h = z - n * NHEADS;
  const int wid = threadIdx.x >> 6, lane = threadIdx.x & 63;
  const float* ch = c + h * HIDD;
  float cc[3][4];
#pragma unroll
  for (int k = 0; k < 3; ++k)
    *(float4*)cc[k] = *(const float4*)(ch + k * 256 + lane * 4);
  const int t0 = blockIdx.y * 64 + wid * 16;
#pragma unroll
  for (int tt = 0; tt < 16; ++tt) {
    const int t = t0 + tt;
    float s = 0.f;
    if (t < SEQL) {
      const unsigned short* xr = Xn + (long long)(n * SEQL + t) * HIDD;
#pragma unroll
      for (int k = 0; k < 3; ++k) {
        ushort4 xv = *(const ushort4*)(xr + k * 256 + lane * 4);
        s += bf2f(xv.x) * cc[k][0] + bf2f(xv.y) * cc[k][1]
           + bf2f(xv.z) * cc[k][2] + bf2f(xv.w) * cc[k][3];
      }
    }
    for (int o = 32; o; o >>= 1) s += __shfl_xor(s, o, 64);
    if (lane == 0) D[z * 256 + t] = s;
  }
}

// ---------- per-iter: Xt[n][e][t] = Xnb[n][t][e] (ld 256, rows t>=197 zero) ----------
__global__ __launch_bounds__(256) void xpose(const unsigned short* __restrict__ Xn,
    unsigned short* __restrict__ Xt) {
  __shared__ unsigned short tile[64][72];
  const int n = blockIdx.z;
  const int e0 = blockIdx.x * 64, t0 = blockIdx.y * 64;
  const int tr = threadIdx.x >> 2;
  const int tc = (threadIdx.x & 3) * 16;
  const int t = t0 + tr;
#pragma unroll
  for (int j = 0; j < 2; ++j) {
    int4 v = {0, 0, 0, 0};
    if (t < SEQL)
      v = *(const int4*)(Xn + (long long)(n * SEQL + t) * HIDD + e0 + tc + j * 8);
    *(int4*)&tile[tr][tc + j * 8] = v;
  }
  __syncthreads();
  const int er = threadIdx.x >> 2;
  const int tcc = (threadIdx.x & 3) * 16;
  unsigned short tmp[16];
#pragma unroll
  for (int j = 0; j < 16; ++j) tmp[j] = tile[tcc + j][er];
  unsigned short* drow = Xt + ((long long)n * HIDD + e0 + er) * 256 + t0 + tcc;
  *(int4*)drow = *(int4*)&tmp[0];
  *(int4*)(drow + 8) = *(int4*)&tmp[8];
}

// =================================================================
// gemm_8ph v2 — U projection (N = 9216).
// =================================================================
template<bool BF16C>
__global__ __launch_bounds__(512, 2) void gemm_8ph(
    const unsigned short* __restrict__ A, int lda,
    const unsigned short* __restrict__ B, int ldb,
    void* __restrict__ Cp, int ldc,
    const float* __restrict__ bias, float alpha,
    int M, int N, int K, int gy)
{
  __shared__ alignas(16) unsigned short Abuf[2 * 2 * 128 * 64];
  __shared__ alignas(16) unsigned short Bbuf[2 * 2 * 128 * 64];

  const int nwg = gridDim.x;
  const int qq = nwg >> 3, rr = nwg & 7;
  const int xcd = blockIdx.x & 7, wix = blockIdx.x >> 3;
  const int f = xcd * qq + (xcd < rr ? xcd : rr) + wix;
  const int m0 = (f % gy) * 256, n0 = (f / gy) * 256;

  const int tid = threadIdx.x;
  const int lane = tid & 63, wid = tid >> 6;
  const int wr = wid >> 2, wc = wid & 3;
  const int lr = lane & 15, g = lane >> 4;

  const int srow = tid >> 3;
  const int schunk = ((tid & 7) ^ ((tid >> 3) & 7)) * 8;
  const int wbyte = wid * 1024;
  const int axor = lr & 7;

  const int ktiles = K >> 6;

  f32x4 acc[8][4];
#pragma unroll
  for (int m = 0; m < 8; ++m)
#pragma unroll
    for (int n = 0; n < 4; ++n) acc[m][n] = (f32x4){0.f, 0.f, 0.f, 0.f};

  auto stA = [&](int kt, int h) {
    const unsigned short* src = A + (long long)(m0 + h * 128 + srow) * lda + kt * 64 + schunk;
    char* dst = (char*)Abuf + ((kt & 1) * 2 + h) * 16384 + wbyte;
    gload16(src, dst);
    gload16(src + 64ll * lda, dst + 8192);
  };
  auto stB = [&](int kt, int h) {
    const unsigned short* src = B + (long long)(n0 + h * 128 + srow) * ldb + kt * 64 + schunk;
    char* dst = (char*)Bbuf + ((kt & 1) * 2 + h) * 16384 + wbyte;
    gload16(src, dst);
    gload16(src + 64ll * ldb, dst + 8192);
  };

  stB(0, 0); stB(0, 1); stA(0, 0); stA(0, 1);
  __builtin_amdgcn_s_waitcnt(0x0F72);
  __builtin_amdgcn_sched_barrier(0);
  __builtin_amdgcn_s_barrier();
  __builtin_amdgcn_sched_barrier(0);

  for (int t = 0; t < ktiles; ++t) {
    const int d = t & 1;
    const char* Ab_ = (const char*)Abuf + (d * 2 + wr) * 16384;
    const char* Bb_ = (const char*)Bbuf + (d * 2 + (wc >> 1)) * 16384;
    const int brow = (wc & 1) * 64;
    const bool more = (t + 1 < ktiles);

    short8 a[4][2], bA[2][2], bB[2][2];

    // phase 1
#pragma unroll
    for (int m = 0; m < 4; ++m)
#pragma unroll
      for (int ks = 0; ks < 2; ++ks)
        a[m][ks] = *(const short8*)(Ab_ + (m * 16 + lr) * 128 + ((((ks << 2) | g) ^ axor) << 4));
#pragma unroll
    for (int n = 0; n < 2; ++n)
#pragma unroll
      for (int ks = 0; ks < 2; ++ks)
        bA[n][ks] = *(const short8*)(Bb_ + (brow + n * 16 + lr) * 128 + ((((ks << 2) | g) ^ axor) << 4));
    if (more) stB(t + 1, 0);
    __builtin_amdgcn_sched_barrier(0);
    __builtin_amdgcn_s_barrier();
    __builtin_amdgcn_sched_barrier(0);
    __builtin_amdgcn_s_waitcnt(0xC07F);
    __builtin_amdgcn_sched_barrier(0);
    __builtin_amdgcn_s_setprio(1);
#pragma unroll
    for (int m = 0; m < 4; ++m)
#pragma unroll
      for (int n = 0; n < 2; ++n)
#pragma unroll
        for (int ks = 0; ks < 2; ++ks)
          acc[m][n] = __builtin_amdgcn_mfma_f32_16x16x32_bf16(a[m][ks], bA[n][ks], acc[m][n], 0, 0, 0);
    __builtin_amdgcn_s_setprio(0);
    __builtin_amdgcn_sched_barrier(0);
    __builtin_amdgcn_s_barrier();
    __builtin_amdgcn_sched_barrier(0);

    // phase 2
#pragma unroll
    for (int n = 0; n < 2; ++n)
#pragma unroll
      for (int ks = 0; ks < 2; ++ks)
        bB[n][ks] = *(const short8*)(Bb_ + (brow + (n + 2) * 16 + lr) * 128 + ((((ks << 2) | g) ^ axor) << 4));
    if (more) stB(t + 1, 1);
    if (more) __builtin_amdgcn_s_waitcnt(0x0F74);
    else      __builtin_amdgcn_s_waitcnt(0x0F70);
    __builtin_amdgcn_sched_barrier(0);
    __builtin_amdgcn_s_barrier();
    __builtin_amdgcn_sched_barrier(0);
    __builtin_amdgcn_s_waitcnt(0xC07F);
    __builtin_amdgcn_sched_barrier(0);
    __builtin_amdgcn_s_setprio(1);
#pragma unroll
    for (int m = 0; m < 4; ++m)
#pragma unroll
      for (int n = 0; n < 2; ++n)
#pragma unroll
        for (int ks = 0; ks < 2; ++ks)
          acc[m][n + 2] = __builtin_amdgcn_mfma_f32_16x16x32_bf16(a[m][ks], bB[n][ks], acc[m][n + 2], 0, 0, 0);
    __builtin_amdgcn_s_setprio(0);
    __builtin_amdgcn_sched_barrier(0);
    __builtin_amdgcn_s_barrier();
    __builtin_amdgcn_sched_barrier(0);

    // phase 3
#pragma unroll
    for (int m = 0; m < 4; ++m)
#pragma unroll
      for (int ks = 0; ks < 2; ++ks)
        a[m][ks] = *(const short8*)(Ab_ + (64 + m * 16 + lr) * 128 + ((((ks << 2) | g) ^ axor) << 4));
    if (more) stA(t + 1, 0);
    __builtin_amdgcn_sched_barrier(0);
    __builtin_amdgcn_s_barrier();
    __builtin_amdgcn_sched_barrier(0);
    __builtin_amdgcn_s_waitcnt(0xC07F);
    __builtin_amdgcn_sched_barrier(0);
    __builtin_amdgcn_s_setprio(1);
#pragma unroll
    for (int m = 0; m < 4; ++m)
#pragma unroll
      for (int n = 0; n < 2; ++n)
#pragma unroll
        for (int ks = 0; ks < 2; ++ks)
          acc[m + 4][n + 2] = __builtin_amdgcn_mfma_f32_16x16x32_bf16(a[m][ks], bB[n][ks], acc[m + 4][n + 2], 0, 0, 0);
    __builtin_amdgcn_s_setprio(0);
    __builtin_amdgcn_sched_barrier(0);
    __builtin_amdgcn_s_barrier();
    __builtin_amdgcn_sched_barrier(0);

    // phase 4
    if (more) {
      stA(t + 1, 1);
      __builtin_amdgcn_s_waitcnt(0x0F72);
    }
    __builtin_amdgcn_sched_barrier(0);
    __builtin_amdgcn_s_barrier();
    __builtin_amdgcn_sched_barrier(0);
    __builtin_amdgcn_s_setprio(1);
#pragma unroll
    for (int m = 0; m < 4; ++m)
#pragma unroll
      for (int n = 0; n < 2; ++n)
#pragma unroll
        for (int ks = 0; ks < 2; ++ks)
          acc[m + 4][n] = __builtin_amdgcn_mfma_f32_16x16x32_bf16(a[m][ks], bA[n][ks], acc[m + 4][n], 0, 0, 0);
    __builtin_amdgcn_s_setprio(0);
    __builtin_amdgcn_sched_barrier(0);
    __builtin_amdgcn_s_barrier();
    __builtin_amdgcn_sched_barrier(0);
  }

#pragma unroll
  for (int m = 0; m < 8; ++m) {
#pragma unroll
    for (int n = 0; n < 4; ++n) {
      const int gn = n0 + wc * 64 + n * 16 + lr;
      const float bv = bias ? bias[gn] : 0.f;
#pragma unroll
      for (int r = 0; r < 4; ++r) {
        const int gm = m0 + wr * 128 + m * 16 + g * 4 + r;
        if (gm >= M) continue;
        const float v = acc[m][n][r] * alpha + bv;
        if constexpr (BF16C)
          ((unsigned short*)Cp)[(long long)gm * ldc + gn] = f2bf(v);
        else
          ((float*)Cp)[(long long)gm * ldc + gn] = v;
      }
    }
  }
}

// =================================================================
// gemm_bt: 2-phase pipeline — T / G-attn / W2 / patch-embed / Mt / G prep
// =================================================================
template<int BM, int BN, int WGM, int WGN, bool BF16C>
__global__ __launch_bounds__(256, 2) void gemm_bt(
    const unsigned short* __restrict__ A, long long sAz1, long long sAz2, int lda,
    const unsigned short* __restrict__ B, long long sBz1, long long sBz2, int ldb,
    void* __restrict__ Cp, long long sCz1, long long sCz2, int ldc,
    const float* __restrict__ bias, int zdiv, float alpha,
    int M, int N, int K, int gy)
{
  constexpr int BK = 32;
  constexpr int VM = BM / 64 + BN / 64;
  static_assert(WGM * WGN == 4, "4 waves");
  __shared__ unsigned short As[3][BM * BK];
  __shared__ unsigned short Bs[3][BN * BK];

  const int z  = blockIdx.z;
  const int z1 = z / zdiv, z2 = z - z1 * zdiv;
  const unsigned short* Ab = A + z1 * sAz1 + z2 * sAz2;
  const unsigned short* Bb = B + z1 * sBz1 + z2 * sBz2;
  const long long coff = z1 * sCz1 + z2 * sCz2;

  const int nwg = gridDim.x;
  const int qq = nwg >> 3, rr = nwg & 7;
  const int xcd = blockIdx.x & 7, wix = blockIdx.x >> 3;
  const int f = xcd * qq + (xcd < rr ? xcd : rr) + wix;
  const int m0 = (f % gy) * BM, n0 = (f / gy) * BN;

  const int tid = threadIdx.x;
  const int lane = tid & 63, wid = tid >> 6;
  const int wr = wid / WGN, wc = wid % WGN;
  constexpr int WM = BM / WGM, WN = BN / WGN, TM = WM / 16, TN = WN / 16;
  const int lr = lane & 15, g = lane >> 4;

  const int sr = wid * 16 + (lane >> 2);
  const int sc = (((lane & 3) ^ ((lane >> 3) & 3)) * 8);
  const int wbyte = wid * 1024;

  f32x4 acc[TM][TN];
#pragma unroll
  for (int m = 0; m < TM; ++m)
#pragma unroll
    for (int n = 0; n < TN; ++n) acc[m][n] = (f32x4){0.f, 0.f, 0.f, 0.f};

  auto stage = [&](int bufi, int kt) {
    const int k0 = kt * BK;
#pragma unroll
    for (int u = 0; u < BM / 64; ++u)
      gload16(Ab + (long long)(m0 + u * 64 + sr) * lda + k0 + sc,
              (char*)&As[bufi][0] + u * 4096 + wbyte);
#pragma unroll
    for (int u = 0; u < BN / 64; ++u)
      gload16(Bb + (long long)(n0 + u * 64 + sr) * ldb + k0 + sc,
              (char*)&Bs[bufi][0] + u * 4096 + wbyte);
  };

  const int rchunk = (g ^ ((lr >> 1) & 3)) * 8;

  const int ktiles = K / BK;
  stage(0, 0);
  if (ktiles > 1) stage(1, 1);
  int cur = 0;
  for (int t = 0; t < ktiles; ++t) {
    if (t + 1 < ktiles) __builtin_amdgcn_s_waitcnt(0x0F70 | VM);
    else                __builtin_amdgcn_s_waitcnt(0x0F70);
    __builtin_amdgcn_s_barrier();
    if (t + 2 < ktiles) {
      int nb = cur + 2; if (nb >= 3) nb -= 3;
      stage(nb, t + 2);
    }
    __builtin_amdgcn_sched_barrier(0);

    short8 a[TM], b[TN];
#pragma unroll
    for (int m = 0; m < TM; ++m)
      a[m] = *(const short8*)&As[cur][(wr * WM + m * 16 + lr) * BK + rchunk];
#pragma unroll
    for (int n = 0; n < TN; ++n)
      b[n] = *(const short8*)&Bs[cur][(wc * WN + n * 16 + lr) * BK + rchunk];
#pragma unroll
    for (int m = 0; m < TM; ++m)
#pragma unroll
      for (int n = 0; n < TN; ++n)
        acc[m][n] = __builtin_amdgcn_mfma_f32_16x16x32_bf16(a[m], b[n], acc[m][n], 0, 0, 0);
    cur = (cur == 2) ? 0 : cur + 1;
  }

#pragma unroll
  for (int m = 0; m < TM; ++m) {
#pragma unroll
    for (int n = 0; n < TN; ++n) {
      const int gn = n0 + wc * WN + n * 16 + lr;
      if (gn >= N) continue;
      const float bv = bias ? bias[gn] : 0.f;
#pragma unroll
      for (int r = 0; r < 4; ++r) {
        const int gm = m0 + wr * WM + m * 16 + g * 4 + r;
        if (gm >= M) continue;
        const float v = acc[m][n][r] * alpha + bv;
        if constexpr (BF16C)
          ((unsigned short*)Cp)[coff + (long long)gm * ldc + gn] = f2bf(v);
        else
          ((float*)Cp)[coff + (long long)gm * ldc + gn] = v;
      }
    }
  }
}

// =================================================================
// scores_sm: per z=(n,h), S = scale * (U[h] @ Xnb^T + D) with fused softmax.
// =================================================================
__global__ __launch_bounds__(256, 2) void scores_sm(
    const unsigned short* __restrict__ U, const unsigned short* __restrict__ Xn,
    const float* __restrict__ Dv, unsigned short* __restrict__ P, float scale)
{
  constexpr int BK = 32;
  __shared__ unsigned short As[3][64 * BK];
  __shared__ unsigned short Bs[3][256 * BK];

  const int z  = blockIdx.z;
  const int z1 = z / NHEADS, z2 = z - z1 * NHEADS;
  const unsigned short* Ab = U + (long long)z1 * SEQL * HH + (long long)z2 * HIDD;
  const unsigned short* Bb = Xn + (long long)z1 * SEQL * HIDD;
  unsigned short* Pz = P + (long long)z * SEQL * PLD;

  const int m0 = blockIdx.x * 64;
  const int tid = threadIdx.x;
  const int lane = tid & 63, wid = tid >> 6;
  const int lr = lane & 15, g = lane >> 4;

  const int sr = wid * 16 + (lane >> 2);
  const int sc = (((lane & 3) ^ ((lane >> 3) & 3)) * 8);
  const int wbyte = wid * 1024;
  const int rchunk = (g ^ ((lr >> 1) & 3)) * 8;

  f32x4 acc[16];
#pragma unroll
  for (int n = 0; n < 16; ++n) acc[n] = (f32x4){0.f, 0.f, 0.f, 0.f};

  auto stage = [&](int bufi, int kt) {
    const int k0 = kt * BK;
    gload16(Ab + (long long)(m0 + sr) * HH + k0 + sc, (char*)&As[bufi][0] + wbyte);
#pragma unroll
    for (int u = 0; u < 4; ++u)
      gload16(Bb + (long long)(u * 64 + sr) * HIDD + k0 + sc,
              (char*)&Bs[bufi][0] + u * 4096 + wbyte);
  };

  const int ktiles = HIDD / BK;
  stage(0, 0);
  stage(1, 1);
  int cur = 0;
  for (int t = 0; t < ktiles; ++t) {
    if (t + 1 < ktiles) __builtin_amdgcn_s_waitcnt(0x0F75);
    else                __builtin_amdgcn_s_waitcnt(0x0F70);
    __builtin_amdgcn_s_barrier();
    if (t + 2 < ktiles) {
      int nb = cur + 2; if (nb >= 3) nb -= 3;
      stage(nb, t + 2);
    }
    __builtin_amdgcn_sched_barrier(0);

    short8 a = *(const short8*)&As[cur][(wid * 16 + lr) * BK + rchunk];
#pragma unroll
    for (int n = 0; n < 16; ++n) {
      short8 b = *(const short8*)&Bs[cur][(n * 16 + lr) * BK + rchunk];
      acc[n] = __builtin_amdgcn_mfma_f32_16x16x32_bf16(a, b, acc[n], 0, 0, 0);
    }
    cur = (cur == 2) ? 0 : cur + 1;
  }

  const float* Dz = Dv + z * 256;
  float dv[16];
#pragma unroll
  for (int n = 0; n < 16; ++n) dv[n] = Dz[n * 16 + lr];

  const int growb = m0 + wid * 16 + g * 4;
#pragma unroll
  for (int r = 0; r < 4; ++r) {
    float mx = -1e30f;
#pragma unroll
    for (int n = 0; n < 16; ++n)
      if (n * 16 + lr < SEQL) mx = fmaxf(mx, (acc[n][r] + dv[n]) * scale);
    for (int o = 1; o < 16; o <<= 1) mx = fmaxf(mx, __shfl_xor(mx, o, 64));
    float sum = 0.f;
#pragma unroll
    for (int n = 0; n < 16; ++n) {
      const float e = (n * 16 + lr < SEQL) ? __expf((acc[n][r] + dv[n]) * scale - mx) : 0.f;
      acc[n][r] = e;
      sum += e;
    }
    for (int o = 1; o < 16; o <<= 1) sum += __shfl_xor(sum, o, 64);
    const float inv = 1.f / sum;
    const int grow = growb + r;
    if (grow < SEQL) {
#pragma unroll
      for (int n = 0; n < 16; ++n)
        Pz[(long long)grow * PLD + n * 16 + lr] = f2bf(acc[n][r] * inv);
    }
  }
}

// =================================================================
// head_k: out[n][o] = tanh(Z[n,0,:] . Wh[o,:] + bh[o])
// =================================================================
__global__ __launch_bounds__(256) void head_k(
    const float* __restrict__ Z, const float* __restrict__ Wh,
    const float* __restrict__ bh, float* __restrict__ out)
{
  __shared__ float Zs[NBATCH][HIDD];
  for (int i = threadIdx.x; i < NBATCH * (HIDD / 4); i += 256) {
    const int n = i / (HIDD / 4);
    const int k4 = i - n * (HIDD / 4);
    float4 v = *(const float4*)(Z + (long long)n * SEQL * HIDD + k4 * 4);
    *(float4*)&Zs[n][k4 * 4] = v;
  }
  __syncthreads();

  const int wid = threadIdx.x >> 6, lane = threadIdx.x & 63;
  const int o = blockIdx.x * 4 + wid;
  if (o >= OUTDIM) return;
  const float* wrow = Wh + (long long)o * HIDD;
  float s[NBATCH];
#pragma unroll
  for (int n = 0; n < NBATCH; ++n) s[n] = 0.f;
  for (int k = lane * 4; k < HIDD; k += 256) {
    float4 w = *(const float4*)(wrow + k);
#pragma unroll
    for (int n = 0; n < NBATCH; ++n) {
      float4 zv = *(const float4*)&Zs[n][k];
      s[n] += w.x * zv.x + w.y * zv.y + w.z * zv.z + w.w * zv.w;
    }
  }
#pragma unroll
  for (int n = 0; n < NBATCH; ++n)
    for (int off2 = 32; off2; off2 >>= 1) s[n] += __shfl_xor(s[n], off2, 64);
  if (lane == 0) {
    const float b = bh[o];
#pragma unroll
    for (int n = 0; n < NBATCH; ++n)
      out[n * OUTDIM + o] = tanhf(s[n] + b);
  }
}

// ---------- embed merge ----------
__global__ __launch_bounds__(256) void embed_merge(
    const float* __restrict__ Etmp, const float* __restrict__ cls,
    const float* __restrict__ pos, float* __restrict__ Z)
{
  const int tot = NBATCH * SEQL * HIDD / 4;
  for (int i = blockIdx.x * 256 + threadIdx.x; i < tot; i += gridDim.x * 256) {
    const int n  = i / (SEQL * HIDD / 4);
    const int se = i - n * (SEQL * HIDD / 4);
    const int s  = se / (HIDD / 4);
    const int e4 = se - s * (HIDD / 4);
    float4 pv = ((const float4*)pos)[se];
    float4 src;
    if (s == 0) src = ((const float4*)cls)[e4];
    else        src = ((const float4*)Etmp)[(long long)(n * NPATCH + s - 1) * (HIDD / 4) + e4];
    float4 o;
    o.x = src.x + pv.x; o.y = src.y + pv.y;
    o.z = src.z + pv.z; o.w = src.w + pv.w;
    ((float4*)Z)[i] = o;
  }
}

// ---------- LN partial pass ----------
__global__ __launch_bounds__(256) void ln_part(const float* __restrict__ x, float* __restrict__ part) {
  const int b = blockIdx.x;
  const int n = b >> 4, seg = b & 15;
  const int per = (SEQL * HIDD / 4) / 16;
  const float4* px = (const float4*)(x + (size_t)n * SEQL * HIDD);
  float s = 0.f, q = 0.f;
  for (int i = seg * per + threadIdx.x; i < (seg + 1) * per; i += 256) {
    float4 v = px[i];
    s += v.x + v.y + v.z + v.w;
    q += v.x * v.x + v.y * v.y + v.z * v.z + v.w * v.w;
  }
  for (int o = 32; o; o >>= 1) { s += __shfl_xor(s, o, 64); q += __shfl_xor(q, o, 64); }
  __shared__ float ls[8];
  const int wid = threadIdx.x >> 6, lane = threadIdx.x & 63;
  if (lane == 0) { ls[wid] = s; ls[4 + wid] = q; }
  __syncthreads();
  if (threadIdx.x == 0) {
    part[b] = ls[0] + ls[1] + ls[2] + ls[3];
    part[128 + b] = ls[4] + ls[5] + ls[6] + ls[7];
  }
}

// ---------- fused reduce (KSPLIT=8) + residual(beff) + LN2 partials ----------
__global__ __launch_bounds__(256) void wo_ln_part(
    const float4* __restrict__ Cp, const float4* __restrict__ Z4,
    const float4* __restrict__ bo4, float4* __restrict__ out4,
    float* __restrict__ part)
{
  const int b = blockIdx.x;
  const int n = b >> 4, seg = b & 15;
  const int per = (SEQL * HIDD / 4) / 16;
  const int tot = M_ALL * HIDD / 4;
  const long long base = (long long)n * (SEQL * HIDD / 4);
  float s = 0.f, q = 0.f;
  for (int i = seg * per + threadIdx.x; i < (seg + 1) * per; i += 256) {
    const long long gi = base + i;
    float4 zv = Z4[gi];
    float4 bb = bo4[i % (HIDD / 4)];
    float4 o;
    o.x = zv.x + bb.x; o.y = zv.y + bb.y;
    o.z = zv.z + bb.z; o.w = zv.w + bb.w;
#pragma unroll
    for (int sp = 0; sp < KSPLIT; ++sp) {
      float4 c = Cp[(long long)sp * tot + gi];
      o.x += c.x; o.y += c.y; o.z += c.z; o.w += c.w;
    }
    out4[gi] = o;
    s += o.x + o.y + o.z + o.w;
    q += o.x * o.x + o.y * o.y + o.z * o.z + o.w * o.w;
  }
  for (int o = 32; o; o >>= 1) { s += __shfl_xor(s, o, 64); q += __shfl_xor(q, o, 64); }
  __shared__ float ls[8];
  const int wid = threadIdx.x >> 6, lane = threadIdx.x & 63;
  if (lane == 0) { ls[wid] = s; ls[4 + wid] = q; }
  __syncthreads();
  if (threadIdx.x == 0) {
    part[b] = ls[0] + ls[1] + ls[2] + ls[3];
    part[128 + b] = ls[4] + ls[5] + ls[6] + ls[7];
  }
}

// ---------- LN apply -> bf16 ----------
__global__ __launch_bounds__(256) void ln_apply_bf(const float* __restrict__ x,
    const float* __restrict__ g, const float* __restrict__ b,
    const float* __restrict__ part, unsigned short* __restrict__ y)
{
  __shared__ float ms[8], rs[8];
  if (threadIdx.x < 8) {
    const int n = threadIdx.x;
    float s = 0.f, qv = 0.f;
    for (int j = 0; j < 16; ++j) { s += part[n * 16 + j]; qv += part[128 + n * 16 + j]; }
    const float inv = 1.f / (float)(SEQL * HIDD);
    const float m = s * inv;
    ms[n] = m;
    rs[n] = rsqrtf(qv * inv - m * m + EPSV);
  }
  __syncthreads();
  const int tot = NBATCH * SEQL * HIDD / 4;
  for (int i = blockIdx.x * 256 + threadIdx.x; i < tot; i += gridDim.x * 256) {
    const int n  = i / (SEQL * HIDD / 4);
    const int se = i - n * (SEQL * HIDD / 4);
    const float m = ms[n], r = rs[n];
    float4 xv = ((const float4*)x)[i];
    float4 gv = ((const float4*)g)[se];
    float4 bv = ((const float4*)b)[se];
    ushort4 o;
    o.x = f2bf((xv.x - m) * r * gv.x + bv.x);
    o.y = f2bf((xv.y - m) * r * gv.y + bv.y);
    o.z = f2bf((xv.z - m) * r * gv.z + bv.z);
    o.w = f2bf((xv.w - m) * r * gv.w + bv.w);
    ((ushort4*)y)[i] = o;
  }
}

// ---------------------------------------------------------------
extern "C" void kernel_launch(void* const* d_in, const int* in_sizes, int n_in,
                              void* d_out, int out_size, void* d_ws, size_t ws_size,
                              hipStream_t stream)
{
  const float* X    = (const float*)d_in[0];
  const float* Wp   = (const float*)d_in[1];
  const float* bp   = (const float*)d_in[2];
  const float* cls  = (const float*)d_in[3];
  const float* pos  = (const float*)d_in[4];
  const float* ln1g = (const float*)d_in[5];
  const float* ln1b = (const float*)d_in[6];
  const float* Wq   = (const float*)d_in[7];
  const float* bq   = (const float*)d_in[8];
  const float* Wk   = (const float*)d_in[9];
  const float* bk   = (const float*)d_in[10];
  const float* Wv   = (const float*)d_in[11];
  const float* bv   = (const float*)d_in[12];
  const float* Wo   = (const float*)d_in[13];
  const float* bo   = (const float*)d_in[14];
  const float* ln2g = (const float*)d_in[15];
  const float* ln2b = (const float*)d_in[16];
  const float* W2   = (const float*)d_in[17];
  const float* b2   = (const float*)d_in[18];
  const float* Wh   = (const float*)d_in[19];
  const float* bh   = (const float*)d_in[20];
  float* out = (float*)d_out;
  (void)in_sizes; (void)n_in; (void)out_size; (void)ws_size;

  char* base = (char*)d_ws;
  size_t off = 0;
  auto alloc = [&](size_t bytes) -> char* {
    char* r = base + off;
    off += (bytes + 255) & ~(size_t)255;
    return r;
  };
  const size_t ZB  = (size_t)M_ALL * HIDD * 4;
  const size_t XB  = (size_t)M_ALL * HIDD * 2;
  const size_t DB  = (size_t)NBATCH * NHEADS * 256 * 4;
  const size_t PB  = (size_t)NBATCH * NHEADS * SEQL * PLD * 2;
  const size_t XTB = (size_t)NBATCH * HIDD * 256 * 2;
  const size_t UB  = (size_t)M_ALL * HH * 2;
  const size_t MTB = (size_t)HH * HIDD * 2;
  const size_t CPB = (size_t)KSPLIT * M_ALL * HIDD * 4;  // 38.7 MB

  float*          Z     = (float*)alloc(ZB);
  float*          Ares  = (float*)alloc(ZB);
  unsigned short* Xnb   = (unsigned short*)alloc(XB);
  float*          stats = (float*)alloc(4096);
  float*          Dbuf  = (float*)alloc(DB);
  unsigned short* Pb    = (unsigned short*)alloc(PB);
  unsigned short* Xt    = (unsigned short*)alloc(XTB);
  unsigned short* U     = (unsigned short*)alloc(UB);
  unsigned short* Mt_bf = (unsigned short*)alloc(MTB);
  unsigned short* Gcat  = (unsigned short*)alloc(MTB);
  unsigned short* W2_bf = (unsigned short*)alloc((size_t)HIDD * HIDD * 2);
  float*          cvecb = (float*)alloc((size_t)NHEADS * HIDD * 4);
  float*          beff  = (float*)alloc((size_t)HIDD * 4);
  float*          Cpart = (float*)alloc(CPB);

  // per-call prep scratch aliases:
  unsigned short* Wkt   = U;
  unsigned short* Wqt   = U + (size_t)NHEADS * HIDD * HIDD;
  unsigned short* Wvt   = (unsigned short*)Cpart;
  unsigned short* Wo_bf = (unsigned short*)base;
  unsigned short* Xbf   = Pb;
  unsigned short* Wp_bf = Pb + 425984;
  float*          Etmp  = Cpart;

  const float scale = 1.0f / ((float)HIDD * (float)HIDD);
  const long long sUn = (long long)SEQL * HH;
  const long long sPn = (long long)NHEADS * SEQL * PLD;
  const long long sPh = (long long)SEQL * PLD;
  const long long HH2 = (long long)HIDD * HIDD;
  const int W24 = HIDD * HIDD / 4;

  // ---- per-call weight prep ----
  wtrans<<<dim3(12, 12, NHEADS), 256, 0, stream>>>(Wk, Wkt);
  wtrans<<<dim3(12, 12, NHEADS), 256, 0, stream>>>(Wq, Wqt);
  wtrans<<<dim3(12, 12, NHEADS), 256, 0, stream>>>(Wv, Wvt);
  gemm_bt<64, 64, 2, 2, true><<<dim3(144, 1, NHEADS), 256, 0, stream>>>(
      Wkt, 0, HH2, HIDD,
      Wqt, 0, HH2, HIDD,
      Mt_bf, 0, HH2, HIDD,
      nullptr, NHEADS, 1.0f, HIDD, HIDD, HIDD, 12);
  cvec2<<<dim3(HIDD / 4, NHEADS), 256, 0, stream>>>(Wkt, bq, cvecb);
  cvt_bf<<<dim3(4096), 256, 0, stream>>>((const float4*)Wo, (ushort4*)Wo_bf, HH * HIDD / 4);
  gemm_bt<64, 64, 2, 2, true><<<dim3(144, 1, NHEADS), 256, 0, stream>>>(
      Wo_bf, 0, HIDD, HH,
      Wvt, 0, HH2, HIDD,
      Gcat, 0, HIDD, HH,
      nullptr, NHEADS, 1.0f, HIDD, HIDD, HIDD, 12);
  beff_k<<<dim3(HIDD / 4), 256, 0, stream>>>(Wo, bv, bo, beff);
  cvt_bf<<<dim3(512), 256, 0, stream>>>((const float4*)W2, (ushort4*)W2_bf, W24);
  cvt_bf<<<dim3(392), 256, 0, stream>>>((const float4*)X,  (ushort4*)Xbf,  MPATCH * PATCHD / 4);
  cvt_bf<<<dim3(192), 256, 0, stream>>>((const float4*)Wp, (ushort4*)Wp_bf, HIDD * PATCHD / 4);
  gemm_bt<64, 64, 2, 2, false><<<dim3(25 * (HIDD / 64), 1, 1), 256, 0, stream>>>(
      Xbf, 0, 0, PATCHD, Wp_bf, 0, 0, PATCHD, Etmp, 0, 0, HIDD,
      bp, 1, 1.0f, MPATCH, HIDD, PATCHD, 25);
  embed_merge<<<dim3(1182), 256, 0, stream>>>(Etmp, cls, pos, Z);

  for (int blk = 0; blk < NBLOCKS; ++blk) {
    // ---- LN1 ----
    ln_part<<<dim3(128), 256, 0, stream>>>(Z, stats);
    ln_apply_bf<<<dim3(1182), 256, 0, stream>>>(Z, ln1g, ln1b, stats, Xnb);

    // ---- per-column score bias D + Xnb transpose ----
    dcol<<<dim3(NBATCH * NHEADS, 4), 256, 0, stream>>>(Xnb, cvecb, Dbuf);
    xpose<<<dim3(HIDD / 64, 4, NBATCH), 256, 0, stream>>>(Xnb, Xt);

    // ---- U projection (8-phase): [1576,768] @ [9216,768]^T ----
    gemm_8ph<true><<<dim3((HH / 256) * 7, 1, 1), 512, 0, stream>>>(
        Xnb, HIDD, Mt_bf, HIDD, U, HH,
        nullptr, 1.0f, M_ALL, HH, HIDD, 7);

    // ---- scores (U @ Xnb^T + D) + fused softmax -> Pb ----
    scores_sm<<<dim3(4, 1, NBATCH * NHEADS), 256, 0, stream>>>(
        U, Xnb, Dbuf, Pb, scale);

    // ---- T = P @ Xnb (BN=128); T overwrites U ----
    gemm_bt<64, 128, 2, 2, true><<<dim3(4 * (HIDD / 128), 1, NBATCH * NHEADS), 256, 0, stream>>>(
        Pb, sPn, sPh, PLD,
        Xt, (long long)HIDD * 256, 0, 256,
        U, sUn, HIDD, HH,
        nullptr, NHEADS, 1.0f, SEQL, HIDD, KPV, 4);

    // ---- attn partials (KSPLIT=8: 1200 blocks): Cpart[s] = T[:,sl] @ Gcat[:,sl]^T ----
    gemm_bt<64, 128, 2, 2, false><<<dim3(25 * (HIDD / 128), 1, KSPLIT), 256, 0, stream>>>(
        U, 0, HH / KSPLIT, HH,
        Gcat, 0, HH / KSPLIT, HH,
        Cpart, 0, (long long)M_ALL * HIDD, HIDD,
        nullptr, KSPLIT, 1.0f, M_ALL, HIDD, HH / KSPLIT, 25);

    // ---- fused reduce + residual + beff + LN2 partials ----
    wo_ln_part<<<dim3(128), 256, 0, stream>>>(
        (const float4*)Cpart, (const float4*)Z, (const float4*)beff, (float4*)Ares, stats);
    ln_apply_bf<<<dim3(1182), 256, 0, stream>>>(Ares, ln2g, ln2b, stats, Xnb);

    // ---- W2 ----
    gemm_bt<64, 64, 2, 2, false><<<dim3(25 * (HIDD / 64), 1, 1), 256, 0, stream>>>(
        Xnb, 0, 0, HIDD, W2_bf, 0, 0, HIDD, Z, 0, 0, HIDD,
        b2, 1, 1.0f, M_ALL, HIDD, HIDD, 25);
  }

  // ---- head ----
  head_k<<<dim3((OUTDIM + 3) / 4), 256, 0, stream>>>(Z, Wh, bh, out);
}

// Round 24
// 1351.970 us; speedup vs baseline: 1.0297x; 1.0297x over previous
//
#include <hip/hip_runtime.h>
#include <hip/hip_bf16.h>
#include <math.h>

typedef __hip_bfloat16 bf16;
typedef __attribute__((ext_vector_type(8))) short short8;
typedef __attribute__((ext_vector_type(4))) float f32x4;

#define HIDD   768
#define SEQL   197
#define NPATCH 196
#define PATCHD 256
#define NHEADS 12
#define NBATCH 8
#define OUTDIM 1000
#define NBLOCKS 6
#define EPSV   1e-5f
#define HH     (NHEADS * HIDD)       /* 9216 */
#define M_ALL  (NBATCH * SEQL)       /* 1576 */
#define MPATCH (NBATCH * NPATCH)     /* 1568 */
#define PLD    256
#define KPV    224
#define KSPLIT 4

// ---------- helpers ----------
__device__ __forceinline__ unsigned short f2bf(float f) {
  union { bf16 h; unsigned short u; } cv; cv.h = __float2bfloat16(f); return cv.u;
}
__device__ __forceinline__ float bf2f(unsigned short u) {
  union { unsigned int i; float f; } w; w.i = ((unsigned int)u) << 16; return w.f;
}

typedef __attribute__((address_space(3))) unsigned int lds_uint;
typedef __attribute__((address_space(1))) const unsigned int g_uint;
__device__ __forceinline__ void gload16(const void* g, void* l) {
  __builtin_amdgcn_global_load_lds((g_uint*)g, (lds_uint*)l, 16, 0, 0);
}

// ---------- fp32 -> bf16 convert ----------
__global__ __launch_bounds__(256) void cvt_bf(const float4* __restrict__ src,
                                              ushort4* __restrict__ dst, int n4) {
  for (int i = blockIdx.x * 256 + threadIdx.x; i < n4; i += gridDim.x * 256) {
    float4 v = src[i];
    ushort4 o;
    o.x = f2bf(v.x); o.y = f2bf(v.y); o.z = f2bf(v.z); o.w = f2bf(v.w);
    dst[i] = o;
  }
}

// ---------- per-call: tiled fp32->bf16 per-head transpose  Dst[h][c][r] = S[h][r][c] ----------
__global__ __launch_bounds__(256) void wtrans(const float* __restrict__ S,
    unsigned short* __restrict__ Dst) {
  __shared__ unsigned short tile[64][72];
  const int h = blockIdx.z;
  const int c0 = blockIdx.x * 64, r0 = blockIdx.y * 64;
  const long long base = (long long)h * HIDD * HIDD;
  const int tr = threadIdx.x >> 2;
  const int tc = (threadIdx.x & 3) * 16;
#pragma unroll
  for (int j = 0; j < 4; ++j) {
    float4 v = *(const float4*)(S + base + (long long)(r0 + tr) * HIDD + c0 + tc + j * 4);
    tile[tr][tc + j * 4 + 0] = f2bf(v.x);
    tile[tr][tc + j * 4 + 1] = f2bf(v.y);
    tile[tr][tc + j * 4 + 2] = f2bf(v.z);
    tile[tr][tc + j * 4 + 3] = f2bf(v.w);
  }
  __syncthreads();
  const int er = threadIdx.x >> 2;
  const int ec = (threadIdx.x & 3) * 16;
  unsigned short tmp[16];
#pragma unroll
  for (int j = 0; j < 16; ++j) tmp[j] = tile[ec + j][er];
  unsigned short* drow = Dst + ((long long)h * HIDD + c0 + er) * HIDD + r0 + ec;
  *(int4*)drow = *(int4*)&tmp[0];
  *(int4*)(drow + 8) = *(int4*)&tmp[8];
}

// ---------- per-call: c[h][d'] = Wkt_bf[h][d'] . bq[h]  (wave per output) ----------
__global__ __launch_bounds__(256) void cvec2(const unsigned short* __restrict__ Wkt,
    const float* __restrict__ bq, float* __restrict__ c) {
  const int h = blockIdx.y;
  const int dp = blockIdx.x * 4 + (threadIdx.x >> 6);
  const int lane = threadIdx.x & 63;
  const unsigned short* row = Wkt + ((long long)h * HIDD + dp) * HIDD;
  const float* b = bq + h * HIDD;
  float s = 0.f;
  for (int e = lane * 4; e < HIDD; e += 256) {
    ushort4 w = *(const ushort4*)(row + e);
    s += bf2f(w.x) * b[e] + bf2f(w.y) * b[e + 1]
       + bf2f(w.z) * b[e + 2] + bf2f(w.w) * b[e + 3];
  }
  for (int o = 32; o; o >>= 1) s += __shfl_xor(s, o, 64);
  if (lane == 0) c[h * HIDD + dp] = s;
}

// ---------- one-time: beff[d] = bo[d] + Wo[d,:] . bv ----------
__global__ __launch_bounds__(256) void beff_k(const float* __restrict__ Wo,
    const float* __restrict__ bv, const float* __restrict__ bo,
    float* __restrict__ beff) {
  const int dout = blockIdx.x * 4 + (threadIdx.x >> 6);
  const int lane = threadIdx.x & 63;
  const float* row = Wo + (long long)dout * HH;
  float s = 0.f;
  for (int i = lane * 4; i < HH; i += 256) {
    float4 w = *(const float4*)(row + i);
    float4 b = *(const float4*)(bv + i);
    s += w.x * b.x + w.y * b.y + w.z * b.z + w.w * b.w;
  }
  for (int o = 32; o; o >>= 1) s += __shfl_xor(s, o, 64);
  if (lane == 0) beff[dout] = bo[dout] + s;
}

// ---------- per-iter: D[z][t] = c[h] . xnb[n*SEQL+t]  (wave per row) ----------
__global__ __launch_bounds__(256) void dcol(const unsigned short* __restrict__ Xn,
    const float* __restrict__ c, float* __restrict__ D) {
  const int z = blockIdx.x;
  const int n = z / NHEADS, h = z - n * NHEADS;
  const int wid = threadIdx.x >> 6, lane = threadIdx.x & 63;
  const float* ch = c + h * HIDD;
  float cc[3][4];
#pragma unroll
  for (int k = 0; k < 3; ++k)
    *(float4*)cc[k] = *(const float4*)(ch + k * 256 + lane * 4);
  const int t0 = blockIdx.y * 64 + wid * 16;
#pragma unroll
  for (int tt = 0; tt < 16; ++tt) {
    const int t = t0 + tt;
    float s = 0.f;
    if (t < SEQL) {
      const unsigned short* xr = Xn + (long long)(n * SEQL + t) * HIDD;
#pragma unroll
      for (int k = 0; k < 3; ++k) {
        ushort4 xv = *(const ushort4*)(xr + k * 256 + lane * 4);
        s += bf2f(xv.x) * cc[k][0] + bf2f(xv.y) * cc[k][1]
           + bf2f(xv.z) * cc[k][2] + bf2f(xv.w) * cc[k][3];
      }
    }
    for (int o = 32; o; o >>= 1) s += __shfl_xor(s, o, 64);
    if (lane == 0) D[z * 256 + t] = s;
  }
}

// ---------- per-iter: Xt[n][e][t] = Xnb[n][t][e] (ld 256, rows t>=197 zero) ----------
__global__ __launch_bounds__(256) void xpose(const unsigned short* __restrict__ Xn,
    unsigned short* __restrict__ Xt) {
  __shared__ unsigned short tile[64][72];
  const int n = blockIdx.z;
  const int e0 = blockIdx.x * 64, t0 = blockIdx.y * 64;
  const int tr = threadIdx.x >> 2;
  const int tc = (threadIdx.x & 3) * 16;
  const int t = t0 + tr;
#pragma unroll
  for (int j = 0; j < 2; ++j) {
    int4 v = {0, 0, 0, 0};
    if (t < SEQL)
      v = *(const int4*)(Xn + (long long)(n * SEQL + t) * HIDD + e0 + tc + j * 8);
    *(int4*)&tile[tr][tc + j * 8] = v;
  }
  __syncthreads();
  const int er = threadIdx.x >> 2;
  const int tcc = (threadIdx.x & 3) * 16;
  unsigned short tmp[16];
#pragma unroll
  for (int j = 0; j < 16; ++j) tmp[j] = tile[tcc + j][er];
  unsigned short* drow = Xt + ((long long)n * HIDD + e0 + er) * 256 + t0 + tcc;
  *(int4*)drow = *(int4*)&tmp[0];
  *(int4*)(drow + 8) = *(int4*)&tmp[8];
}

// =================================================================
// gemm_8ph v2 — U projection (N = 9216).
// =================================================================
template<bool BF16C>
__global__ __launch_bounds__(512, 2) void gemm_8ph(
    const unsigned short* __restrict__ A, int lda,
    const unsigned short* __restrict__ B, int ldb,
    void* __restrict__ Cp, int ldc,
    const float* __restrict__ bias, float alpha,
    int M, int N, int K, int gy)
{
  __shared__ alignas(16) unsigned short Abuf[2 * 2 * 128 * 64];
  __shared__ alignas(16) unsigned short Bbuf[2 * 2 * 128 * 64];

  const int nwg = gridDim.x;
  const int qq = nwg >> 3, rr = nwg & 7;
  const int xcd = blockIdx.x & 7, wix = blockIdx.x >> 3;
  const int f = xcd * qq + (xcd < rr ? xcd : rr) + wix;
  const int m0 = (f % gy) * 256, n0 = (f / gy) * 256;

  const int tid = threadIdx.x;
  const int lane = tid & 63, wid = tid >> 6;
  const int wr = wid >> 2, wc = wid & 3;
  const int lr = lane & 15, g = lane >> 4;

  const int srow = tid >> 3;
  const int schunk = ((tid & 7) ^ ((tid >> 3) & 7)) * 8;
  const int wbyte = wid * 1024;
  const int axor = lr & 7;

  const int ktiles = K >> 6;

  f32x4 acc[8][4];
#pragma unroll
  for (int m = 0; m < 8; ++m)
#pragma unroll
    for (int n = 0; n < 4; ++n) acc[m][n] = (f32x4){0.f, 0.f, 0.f, 0.f};

  auto stA = [&](int kt, int h) {
    const unsigned short* src = A + (long long)(m0 + h * 128 + srow) * lda + kt * 64 + schunk;
    char* dst = (char*)Abuf + ((kt & 1) * 2 + h) * 16384 + wbyte;
    gload16(src, dst);
    gload16(src + 64ll * lda, dst + 8192);
  };
  auto stB = [&](int kt, int h) {
    const unsigned short* src = B + (long long)(n0 + h * 128 + srow) * ldb + kt * 64 + schunk;
    char* dst = (char*)Bbuf + ((kt & 1) * 2 + h) * 16384 + wbyte;
    gload16(src, dst);
    gload16(src + 64ll * ldb, dst + 8192);
  };

  stB(0, 0); stB(0, 1); stA(0, 0); stA(0, 1);
  __builtin_amdgcn_s_waitcnt(0x0F72);
  __builtin_amdgcn_sched_barrier(0);
  __builtin_amdgcn_s_barrier();
  __builtin_amdgcn_sched_barrier(0);

  for (int t = 0; t < ktiles; ++t) {
    const int d = t & 1;
    const char* Ab_ = (const char*)Abuf + (d * 2 + wr) * 16384;
    const char* Bb_ = (const char*)Bbuf + (d * 2 + (wc >> 1)) * 16384;
    const int brow = (wc & 1) * 64;
    const bool more = (t + 1 < ktiles);

    short8 a[4][2], bA[2][2], bB[2][2];

    // phase 1
#pragma unroll
    for (int m = 0; m < 4; ++m)
#pragma unroll
      for (int ks = 0; ks < 2; ++ks)
        a[m][ks] = *(const short8*)(Ab_ + (m * 16 + lr) * 128 + ((((ks << 2) | g) ^ axor) << 4));
#pragma unroll
    for (int n = 0; n < 2; ++n)
#pragma unroll
      for (int ks = 0; ks < 2; ++ks)
        bA[n][ks] = *(const short8*)(Bb_ + (brow + n * 16 + lr) * 128 + ((((ks << 2) | g) ^ axor) << 4));
    if (more) stB(t + 1, 0);
    __builtin_amdgcn_sched_barrier(0);
    __builtin_amdgcn_s_barrier();
    __builtin_amdgcn_sched_barrier(0);
    __builtin_amdgcn_s_waitcnt(0xC07F);
    __builtin_amdgcn_sched_barrier(0);
    __builtin_amdgcn_s_setprio(1);
#pragma unroll
    for (int m = 0; m < 4; ++m)
#pragma unroll
      for (int n = 0; n < 2; ++n)
#pragma unroll
        for (int ks = 0; ks < 2; ++ks)
          acc[m][n] = __builtin_amdgcn_mfma_f32_16x16x32_bf16(a[m][ks], bA[n][ks], acc[m][n], 0, 0, 0);
    __builtin_amdgcn_s_setprio(0);
    __builtin_amdgcn_sched_barrier(0);
    __builtin_amdgcn_s_barrier();
    __builtin_amdgcn_sched_barrier(0);

    // phase 2
#pragma unroll
    for (int n = 0; n < 2; ++n)
#pragma unroll
      for (int ks = 0; ks < 2; ++ks)
        bB[n][ks] = *(const short8*)(Bb_ + (brow + (n + 2) * 16 + lr) * 128 + ((((ks << 2) | g) ^ axor) << 4));
    if (more) stB(t + 1, 1);
    if (more) __builtin_amdgcn_s_waitcnt(0x0F74);
    else      __builtin_amdgcn_s_waitcnt(0x0F70);
    __builtin_amdgcn_sched_barrier(0);
    __builtin_amdgcn_s_barrier();
    __builtin_amdgcn_sched_barrier(0);
    __builtin_amdgcn_s_waitcnt(0xC07F);
    __builtin_amdgcn_sched_barrier(0);
    __builtin_amdgcn_s_setprio(1);
#pragma unroll
    for (int m = 0; m < 4; ++m)
#pragma unroll
      for (int n = 0; n < 2; ++n)
#pragma unroll
        for (int ks = 0; ks < 2; ++ks)
          acc[m][n + 2] = __builtin_amdgcn_mfma_f32_16x16x32_bf16(a[m][ks], bB[n][ks], acc[m][n + 2], 0, 0, 0);
    __builtin_amdgcn_s_setprio(0);
    __builtin_amdgcn_sched_barrier(0);
    __builtin_amdgcn_s_barrier();
    __builtin_amdgcn_sched_barrier(0);

    // phase 3
#pragma unroll
    for (int m = 0; m < 4; ++m)
#pragma unroll
      for (int ks = 0; ks < 2; ++ks)
        a[m][ks] = *(const short8*)(Ab_ + (64 + m * 16 + lr) * 128 + ((((ks << 2) | g) ^ axor) << 4));
    if (more) stA(t + 1, 0);
    __builtin_amdgcn_sched_barrier(0);
    __builtin_amdgcn_s_barrier();
    __builtin_amdgcn_sched_barrier(0);
    __builtin_amdgcn_s_waitcnt(0xC07F);
    __builtin_amdgcn_sched_barrier(0);
    __builtin_amdgcn_s_setprio(1);
#pragma unroll
    for (int m = 0; m < 4; ++m)
#pragma unroll
      for (int n = 0; n < 2; ++n)
#pragma unroll
        for (int ks = 0; ks < 2; ++ks)
          acc[m + 4][n + 2] = __builtin_amdgcn_mfma_f32_16x16x32_bf16(a[m][ks], bB[n][ks], acc[m + 4][n + 2], 0, 0, 0);
    __builtin_amdgcn_s_setprio(0);
    __builtin_amdgcn_sched_barrier(0);
    __builtin_amdgcn_s_barrier();
    __builtin_amdgcn_sched_barrier(0);

    // phase 4
    if (more) {
      stA(t + 1, 1);
      __builtin_amdgcn_s_waitcnt(0x0F72);
    }
    __builtin_amdgcn_sched_barrier(0);
    __builtin_amdgcn_s_barrier();
    __builtin_amdgcn_sched_barrier(0);
    __builtin_amdgcn_s_setprio(1);
#pragma unroll
    for (int m = 0; m < 4; ++m)
#pragma unroll
      for (int n = 0; n < 2; ++n)
#pragma unroll
        for (int ks = 0; ks < 2; ++ks)
          acc[m + 4][n] = __builtin_amdgcn_mfma_f32_16x16x32_bf16(a[m][ks], bA[n][ks], acc[m + 4][n], 0, 0, 0);
    __builtin_amdgcn_s_setprio(0);
    __builtin_amdgcn_sched_barrier(0);
    __builtin_amdgcn_s_barrier();
    __builtin_amdgcn_sched_barrier(0);
  }

#pragma unroll
  for (int m = 0; m < 8; ++m) {
#pragma unroll
    for (int n = 0; n < 4; ++n) {
      const int gn = n0 + wc * 64 + n * 16 + lr;
      const float bv = bias ? bias[gn] : 0.f;
#pragma unroll
      for (int r = 0; r < 4; ++r) {
        const int gm = m0 + wr * 128 + m * 16 + g * 4 + r;
        if (gm >= M) continue;
        const float v = acc[m][n][r] * alpha + bv;
        if constexpr (BF16C)
          ((unsigned short*)Cp)[(long long)gm * ldc + gn] = f2bf(v);
        else
          ((float*)Cp)[(long long)gm * ldc + gn] = v;
      }
    }
  }
}

// =================================================================
// gemm_bt: 2-phase pipeline — T / G-attn / W2 / patch-embed / Mt / G prep
// =================================================================
template<int BM, int BN, int WGM, int WGN, bool BF16C>
__global__ __launch_bounds__(256, 2) void gemm_bt(
    const unsigned short* __restrict__ A, long long sAz1, long long sAz2, int lda,
    const unsigned short* __restrict__ B, long long sBz1, long long sBz2, int ldb,
    void* __restrict__ Cp, long long sCz1, long long sCz2, int ldc,
    const float* __restrict__ bias, int zdiv, float alpha,
    int M, int N, int K, int gy)
{
  constexpr int BK = 32;
  constexpr int VM = BM / 64 + BN / 64;
  static_assert(WGM * WGN == 4, "4 waves");
  __shared__ unsigned short As[3][BM * BK];
  __shared__ unsigned short Bs[3][BN * BK];

  const int z  = blockIdx.z;
  const int z1 = z / zdiv, z2 = z - z1 * zdiv;
  const unsigned short* Ab = A + z1 * sAz1 + z2 * sAz2;
  const unsigned short* Bb = B + z1 * sBz1 + z2 * sBz2;
  const long long coff = z1 * sCz1 + z2 * sCz2;

  const int nwg = gridDim.x;
  const int qq = nwg >> 3, rr = nwg & 7;
  const int xcd = blockIdx.x & 7, wix = blockIdx.x >> 3;
  const int f = xcd * qq + (xcd < rr ? xcd : rr) + wix;
  const int m0 = (f % gy) * BM, n0 = (f / gy) * BN;

  const int tid = threadIdx.x;
  const int lane = tid & 63, wid = tid >> 6;
  const int wr = wid / WGN, wc = wid % WGN;
  constexpr int WM = BM / WGM, WN = BN / WGN, TM = WM / 16, TN = WN / 16;
  const int lr = lane & 15, g = lane >> 4;

  const int sr = wid * 16 + (lane >> 2);
  const int sc = (((lane & 3) ^ ((lane >> 3) & 3)) * 8);
  const int wbyte = wid * 1024;

  f32x4 acc[TM][TN];
#pragma unroll
  for (int m = 0; m < TM; ++m)
#pragma unroll
    for (int n = 0; n < TN; ++n) acc[m][n] = (f32x4){0.f, 0.f, 0.f, 0.f};

  auto stage = [&](int bufi, int kt) {
    const int k0 = kt * BK;
#pragma unroll
    for (int u = 0; u < BM / 64; ++u)
      gload16(Ab + (long long)(m0 + u * 64 + sr) * lda + k0 + sc,
              (char*)&As[bufi][0] + u * 4096 + wbyte);
#pragma unroll
    for (int u = 0; u < BN / 64; ++u)
      gload16(Bb + (long long)(n0 + u * 64 + sr) * ldb + k0 + sc,
              (char*)&Bs[bufi][0] + u * 4096 + wbyte);
  };

  const int rchunk = (g ^ ((lr >> 1) & 3)) * 8;

  const int ktiles = K / BK;
  stage(0, 0);
  if (ktiles > 1) stage(1, 1);
  int cur = 0;
  for (int t = 0; t < ktiles; ++t) {
    if (t + 1 < ktiles) __builtin_amdgcn_s_waitcnt(0x0F70 | VM);
    else                __builtin_amdgcn_s_waitcnt(0x0F70);
    __builtin_amdgcn_s_barrier();
    if (t + 2 < ktiles) {
      int nb = cur + 2; if (nb >= 3) nb -= 3;
      stage(nb, t + 2);
    }
    __builtin_amdgcn_sched_barrier(0);

    short8 a[TM], b[TN];
#pragma unroll
    for (int m = 0; m < TM; ++m)
      a[m] = *(const short8*)&As[cur][(wr * WM + m * 16 + lr) * BK + rchunk];
#pragma unroll
    for (int n = 0; n < TN; ++n)
      b[n] = *(const short8*)&Bs[cur][(wc * WN + n * 16 + lr) * BK + rchunk];
#pragma unroll
    for (int m = 0; m < TM; ++m)
#pragma unroll
      for (int n = 0; n < TN; ++n)
        acc[m][n] = __builtin_amdgcn_mfma_f32_16x16x32_bf16(a[m], b[n], acc[m][n], 0, 0, 0);
    cur = (cur == 2) ? 0 : cur + 1;
  }

#pragma unroll
  for (int m = 0; m < TM; ++m) {
#pragma unroll
    for (int n = 0; n < TN; ++n) {
      const int gn = n0 + wc * WN + n * 16 + lr;
      if (gn >= N) continue;
      const float bv = bias ? bias[gn] : 0.f;
#pragma unroll
      for (int r = 0; r < 4; ++r) {
        const int gm = m0 + wr * WM + m * 16 + g * 4 + r;
        if (gm >= M) continue;
        const float v = acc[m][n][r] * alpha + bv;
        if constexpr (BF16C)
          ((unsigned short*)Cp)[coff + (long long)gm * ldc + gn] = f2bf(v);
        else
          ((float*)Cp)[coff + (long long)gm * ldc + gn] = v;
      }
    }
  }
}

// =================================================================
// scores_sm: per z=(n,h), S = scale * (U[h] @ Xnb^T + D) with fused softmax.
// =================================================================
__global__ __launch_bounds__(256, 2) void scores_sm(
    const unsigned short* __restrict__ U, const unsigned short* __restrict__ Xn,
    const float* __restrict__ Dv, unsigned short* __restrict__ P, float scale)
{
  constexpr int BK = 32;
  __shared__ unsigned short As[3][64 * BK];
  __shared__ unsigned short Bs[3][256 * BK];

  const int z  = blockIdx.z;
  const int z1 = z / NHEADS, z2 = z - z1 * NHEADS;
  const unsigned short* Ab = U + (long long)z1 * SEQL * HH + (long long)z2 * HIDD;
  const unsigned short* Bb = Xn + (long long)z1 * SEQL * HIDD;
  unsigned short* Pz = P + (long long)z * SEQL * PLD;

  const int m0 = blockIdx.x * 64;
  const int tid = threadIdx.x;
  const int lane = tid & 63, wid = tid >> 6;
  const int lr = lane & 15, g = lane >> 4;

  const int sr = wid * 16 + (lane >> 2);
  const int sc = (((lane & 3) ^ ((lane >> 3) & 3)) * 8);
  const int wbyte = wid * 1024;
  const int rchunk = (g ^ ((lr >> 1) & 3)) * 8;

  f32x4 acc[16];
#pragma unroll
  for (int n = 0; n < 16; ++n) acc[n] = (f32x4){0.f, 0.f, 0.f, 0.f};

  auto stage = [&](int bufi, int kt) {
    const int k0 = kt * BK;
    gload16(Ab + (long long)(m0 + sr) * HH + k0 + sc, (char*)&As[bufi][0] + wbyte);
#pragma unroll
    for (int u = 0; u < 4; ++u)
      gload16(Bb + (long long)(u * 64 + sr) * HIDD + k0 + sc,
              (char*)&Bs[bufi][0] + u * 4096 + wbyte);
  };

  const int ktiles = HIDD / BK;
  stage(0, 0);
  stage(1, 1);
  int cur = 0;
  for (int t = 0; t < ktiles; ++t) {
    if (t + 1 < ktiles) __builtin_amdgcn_s_waitcnt(0x0F75);
    else                __builtin_amdgcn_s_waitcnt(0x0F70);
    __builtin_amdgcn_s_barrier();
    if (t + 2 < ktiles) {
      int nb = cur + 2; if (nb >= 3) nb -= 3;
      stage(nb, t + 2);
    }
    __builtin_amdgcn_sched_barrier(0);

    short8 a = *(const short8*)&As[cur][(wid * 16 + lr) * BK + rchunk];
#pragma unroll
    for (int n = 0; n < 16; ++n) {
      short8 b = *(const short8*)&Bs[cur][(n * 16 + lr) * BK + rchunk];
      acc[n] = __builtin_amdgcn_mfma_f32_16x16x32_bf16(a, b, acc[n], 0, 0, 0);
    }
    cur = (cur == 2) ? 0 : cur + 1;
  }

  const float* Dz = Dv + z * 256;
  float dv[16];
#pragma unroll
  for (int n = 0; n < 16; ++n) dv[n] = Dz[n * 16 + lr];

  const int growb = m0 + wid * 16 + g * 4;
#pragma unroll
  for (int r = 0; r < 4; ++r) {
    float mx = -1e30f;
#pragma unroll
    for (int n = 0; n < 16; ++n)
      if (n * 16 + lr < SEQL) mx = fmaxf(mx, (acc[n][r] + dv[n]) * scale);
    for (int o = 1; o < 16; o <<= 1) mx = fmaxf(mx, __shfl_xor(mx, o, 64));
    float sum = 0.f;
#pragma unroll
    for (int n = 0; n < 16; ++n) {
      const float e = (n * 16 + lr < SEQL) ? __expf((acc[n][r] + dv[n]) * scale - mx) : 0.f;
      acc[n][r] = e;
      sum += e;
    }
    for (int o = 1; o < 16; o <<= 1) sum += __shfl_xor(sum, o, 64);
    const float inv = 1.f / sum;
    const int grow = growb + r;
    if (grow < SEQL) {
#pragma unroll
      for (int n = 0; n < 16; ++n)
        Pz[(long long)grow * PLD + n * 16 + lr] = f2bf(acc[n][r] * inv);
    }
  }
}

// =================================================================
// head_k: out[n][o] = tanh(Z[n,0,:] . Wh[o,:] + bh[o])
// =================================================================
__global__ __launch_bounds__(256) void head_k(
    const float* __restrict__ Z, const float* __restrict__ Wh,
    const float* __restrict__ bh, float* __restrict__ out)
{
  __shared__ float Zs[NBATCH][HIDD];
  for (int i = threadIdx.x; i < NBATCH * (HIDD / 4); i += 256) {
    const int n = i / (HIDD / 4);
    const int k4 = i - n * (HIDD / 4);
    float4 v = *(const float4*)(Z + (long long)n * SEQL * HIDD + k4 * 4);
    *(float4*)&Zs[n][k4 * 4] = v;
  }
  __syncthreads();

  const int wid = threadIdx.x >> 6, lane = threadIdx.x & 63;
  const int o = blockIdx.x * 4 + wid;
  if (o >= OUTDIM) return;
  const float* wrow = Wh + (long long)o * HIDD;
  float s[NBATCH];
#pragma unroll
  for (int n = 0; n < NBATCH; ++n) s[n] = 0.f;
  for (int k = lane * 4; k < HIDD; k += 256) {
    float4 w = *(const float4*)(wrow + k);
#pragma unroll
    for (int n = 0; n < NBATCH; ++n) {
      float4 zv = *(const float4*)&Zs[n][k];
      s[n] += w.x * zv.x + w.y * zv.y + w.z * zv.z + w.w * zv.w;
    }
  }
#pragma unroll
  for (int n = 0; n < NBATCH; ++n)
    for (int off2 = 32; off2; off2 >>= 1) s[n] += __shfl_xor(s[n], off2, 64);
  if (lane == 0) {
    const float b = bh[o];
#pragma unroll
    for (int n = 0; n < NBATCH; ++n)
      out[n * OUTDIM + o] = tanhf(s[n] + b);
  }
}

// ---------- embed merge ----------
__global__ __launch_bounds__(256) void embed_merge(
    const float* __restrict__ Etmp, const float* __restrict__ cls,
    const float* __restrict__ pos, float* __restrict__ Z)
{
  const int tot = NBATCH * SEQL * HIDD / 4;
  for (int i = blockIdx.x * 256 + threadIdx.x; i < tot; i += gridDim.x * 256) {
    const int n  = i / (SEQL * HIDD / 4);
    const int se = i - n * (SEQL * HIDD / 4);
    const int s  = se / (HIDD / 4);
    const int e4 = se - s * (HIDD / 4);
    float4 pv = ((const float4*)pos)[se];
    float4 src;
    if (s == 0) src = ((const float4*)cls)[e4];
    else        src = ((const float4*)Etmp)[(long long)(n * NPATCH + s - 1) * (HIDD / 4) + e4];
    float4 o;
    o.x = src.x + pv.x; o.y = src.y + pv.y;
    o.z = src.z + pv.z; o.w = src.w + pv.w;
    ((float4*)Z)[i] = o;
  }
}

// ---------- LN partial pass ----------
__global__ __launch_bounds__(256) void ln_part(const float* __restrict__ x, float* __restrict__ part) {
  const int b = blockIdx.x;
  const int n = b >> 4, seg = b & 15;
  const int per = (SEQL * HIDD / 4) / 16;
  const float4* px = (const float4*)(x + (size_t)n * SEQL * HIDD);
  float s = 0.f, q = 0.f;
  for (int i = seg * per + threadIdx.x; i < (seg + 1) * per; i += 256) {
    float4 v = px[i];
    s += v.x + v.y + v.z + v.w;
    q += v.x * v.x + v.y * v.y + v.z * v.z + v.w * v.w;
  }
  for (int o = 32; o; o >>= 1) { s += __shfl_xor(s, o, 64); q += __shfl_xor(q, o, 64); }
  __shared__ float ls[8];
  const int wid = threadIdx.x >> 6, lane = threadIdx.x & 63;
  if (lane == 0) { ls[wid] = s; ls[4 + wid] = q; }
  __syncthreads();
  if (threadIdx.x == 0) {
    part[b] = ls[0] + ls[1] + ls[2] + ls[3];
    part[128 + b] = ls[4] + ls[5] + ls[6] + ls[7];
  }
}

// ---------- fused reduce (KSPLIT) + residual(beff) + LN2 partials ----------
__global__ __launch_bounds__(256) void wo_ln_part(
    const float4* __restrict__ Cp, const float4* __restrict__ Z4,
    const float4* __restrict__ bo4, float4* __restrict__ out4,
    float* __restrict__ part)
{
  const int b = blockIdx.x;
  const int n = b >> 4, seg = b & 15;
  const int per = (SEQL * HIDD / 4) / 16;
  const int tot = M_ALL * HIDD / 4;
  const long long base = (long long)n * (SEQL * HIDD / 4);
  float s = 0.f, q = 0.f;
  for (int i = seg * per + threadIdx.x; i < (seg + 1) * per; i += 256) {
    const long long gi = base + i;
    float4 zv = Z4[gi];
    float4 bb = bo4[i % (HIDD / 4)];
    float4 o;
    o.x = zv.x + bb.x; o.y = zv.y + bb.y;
    o.z = zv.z + bb.z; o.w = zv.w + bb.w;
#pragma unroll
    for (int sp = 0; sp < KSPLIT; ++sp) {
      float4 c = Cp[(long long)sp * tot + gi];
      o.x += c.x; o.y += c.y; o.z += c.z; o.w += c.w;
    }
    out4[gi] = o;
    s += o.x + o.y + o.z + o.w;
    q += o.x * o.x + o.y * o.y + o.z * o.z + o.w * o.w;
  }
  for (int o = 32; o; o >>= 1) { s += __shfl_xor(s, o, 64); q += __shfl_xor(q, o, 64); }
  __shared__ float ls[8];
  const int wid = threadIdx.x >> 6, lane = threadIdx.x & 63;
  if (lane == 0) { ls[wid] = s; ls[4 + wid] = q; }
  __syncthreads();
  if (threadIdx.x == 0) {
    part[b] = ls[0] + ls[1] + ls[2] + ls[3];
    part[128 + b] = ls[4] + ls[5] + ls[6] + ls[7];
  }
}

// ---------- LN apply -> bf16 ----------
__global__ __launch_bounds__(256) void ln_apply_bf(const float* __restrict__ x,
    const float* __restrict__ g, const float* __restrict__ b,
    const float* __restrict__ part, unsigned short* __restrict__ y)
{
  __shared__ float ms[8], rs[8];
  if (threadIdx.x < 8) {
    const int n = threadIdx.x;
    float s = 0.f, qv = 0.f;
    for (int j = 0; j < 16; ++j) { s += part[n * 16 + j]; qv += part[128 + n * 16 + j]; }
    const float inv = 1.f / (float)(SEQL * HIDD);
    const float m = s * inv;
    ms[n] = m;
    rs[n] = rsqrtf(qv * inv - m * m + EPSV);
  }
  __syncthreads();
  const int tot = NBATCH * SEQL * HIDD / 4;
  for (int i = blockIdx.x * 256 + threadIdx.x; i < tot; i += gridDim.x * 256) {
    const int n  = i / (SEQL * HIDD / 4);
    const int se = i - n * (SEQL * HIDD / 4);
    const float m = ms[n], r = rs[n];
    float4 xv = ((const float4*)x)[i];
    float4 gv = ((const float4*)g)[se];
    float4 bv = ((const float4*)b)[se];
    ushort4 o;
    o.x = f2bf((xv.x - m) * r * gv.x + bv.x);
    o.y = f2bf((xv.y - m) * r * gv.y + bv.y);
    o.z = f2bf((xv.z - m) * r * gv.z + bv.z);
    o.w = f2bf((xv.w - m) * r * gv.w + bv.w);
    ((ushort4*)y)[i] = o;
  }
}

// ---------------------------------------------------------------
extern "C" void kernel_launch(void* const* d_in, const int* in_sizes, int n_in,
                              void* d_out, int out_size, void* d_ws, size_t ws_size,
                              hipStream_t stream)
{
  const float* X    = (const float*)d_in[0];
  const float* Wp   = (const float*)d_in[1];
  const float* bp   = (const float*)d_in[2];
  const float* cls  = (const float*)d_in[3];
  const float* pos  = (const float*)d_in[4];
  const float* ln1g = (const float*)d_in[5];
  const float* ln1b = (const float*)d_in[6];
  const float* Wq   = (const float*)d_in[7];
  const float* bq   = (const float*)d_in[8];
  const float* Wk   = (const float*)d_in[9];
  const float* bk   = (const float*)d_in[10];
  const float* Wv   = (const float*)d_in[11];
  const float* bv   = (const float*)d_in[12];
  const float* Wo   = (const float*)d_in[13];
  const float* bo   = (const float*)d_in[14];
  const float* ln2g = (const float*)d_in[15];
  const float* ln2b = (const float*)d_in[16];
  const float* W2   = (const float*)d_in[17];
  const float* b2   = (const float*)d_in[18];
  const float* Wh   = (const float*)d_in[19];
  const float* bh   = (const float*)d_in[20];
  float* out = (float*)d_out;
  (void)in_sizes; (void)n_in; (void)out_size; (void)ws_size;

  char* base = (char*)d_ws;
  size_t off = 0;
  auto alloc = [&](size_t bytes) -> char* {
    char* r = base + off;
    off += (bytes + 255) & ~(size_t)255;
    return r;
  };
  const size_t ZB  = (size_t)M_ALL * HIDD * 4;
  const size_t XB  = (size_t)M_ALL * HIDD * 2;
  const size_t DB  = (size_t)NBATCH * NHEADS * 256 * 4;
  const size_t PB  = (size_t)NBATCH * NHEADS * SEQL * PLD * 2;
  const size_t XTB = (size_t)NBATCH * HIDD * 256 * 2;
  const size_t UB  = (size_t)M_ALL * HH * 2;
  const size_t MTB = (size_t)HH * HIDD * 2;
  const size_t CPB = (size_t)KSPLIT * M_ALL * HIDD * 4;

  float*          Z     = (float*)alloc(ZB);
  float*          Ares  = (float*)alloc(ZB);
  unsigned short* Xnb   = (unsigned short*)alloc(XB);
  float*          stats = (float*)alloc(4096);
  float*          Dbuf  = (float*)alloc(DB);
  unsigned short* Pb    = (unsigned short*)alloc(PB);
  unsigned short* Xt    = (unsigned short*)alloc(XTB);
  unsigned short* U     = (unsigned short*)alloc(UB);
  unsigned short* Mt_bf = (unsigned short*)alloc(MTB);
  unsigned short* Gcat  = (unsigned short*)alloc(MTB);
  unsigned short* W2_bf = (unsigned short*)alloc((size_t)HIDD * HIDD * 2);
  float*          cvecb = (float*)alloc((size_t)NHEADS * HIDD * 4);
  float*          beff  = (float*)alloc((size_t)HIDD * 4);
  float*          Cpart = (float*)alloc(CPB);

  // per-call prep scratch aliases:
  unsigned short* Wkt   = U;
  unsigned short* Wqt   = U + (size_t)NHEADS * HIDD * HIDD;
  unsigned short* Wvt   = (unsigned short*)Cpart;
  unsigned short* Wo_bf = (unsigned short*)base;
  unsigned short* Xbf   = Pb;
  unsigned short* Wp_bf = Pb + 425984;
  float*          Etmp  = Cpart;

  const float scale = 1.0f / ((float)HIDD * (float)HIDD);
  const long long sUn = (long long)SEQL * HH;
  const long long sPn = (long long)NHEADS * SEQL * PLD;
  const long long sPh = (long long)SEQL * PLD;
  const long long HH2 = (long long)HIDD * HIDD;
  const int W24 = HIDD * HIDD / 4;

  // ---- per-call weight prep ----
  wtrans<<<dim3(12, 12, NHEADS), 256, 0, stream>>>(Wk, Wkt);
  wtrans<<<dim3(12, 12, NHEADS), 256, 0, stream>>>(Wq, Wqt);
  wtrans<<<dim3(12, 12, NHEADS), 256, 0, stream>>>(Wv, Wvt);
  gemm_bt<64, 64, 2, 2, true><<<dim3(144, 1, NHEADS), 256, 0, stream>>>(
      Wkt, 0, HH2, HIDD,
      Wqt, 0, HH2, HIDD,
      Mt_bf, 0, HH2, HIDD,
      nullptr, NHEADS, 1.0f, HIDD, HIDD, HIDD, 12);
  cvec2<<<dim3(HIDD / 4, NHEADS), 256, 0, stream>>>(Wkt, bq, cvecb);
  cvt_bf<<<dim3(4096), 256, 0, stream>>>((const float4*)Wo, (ushort4*)Wo_bf, HH * HIDD / 4);
  gemm_bt<64, 64, 2, 2, true><<<dim3(144, 1, NHEADS), 256, 0, stream>>>(
      Wo_bf, 0, HIDD, HH,
      Wvt, 0, HH2, HIDD,
      Gcat, 0, HIDD, HH,
      nullptr, NHEADS, 1.0f, HIDD, HIDD, HIDD, 12);
  beff_k<<<dim3(HIDD / 4), 256, 0, stream>>>(Wo, bv, bo, beff);
  cvt_bf<<<dim3(512), 256, 0, stream>>>((const float4*)W2, (ushort4*)W2_bf, W24);
  cvt_bf<<<dim3(392), 256, 0, stream>>>((const float4*)X,  (ushort4*)Xbf,  MPATCH * PATCHD / 4);
  cvt_bf<<<dim3(192), 256, 0, stream>>>((const float4*)Wp, (ushort4*)Wp_bf, HIDD * PATCHD / 4);
  gemm_bt<64, 64, 2, 2, false><<<dim3(25 * (HIDD / 64), 1, 1), 256, 0, stream>>>(
      Xbf, 0, 0, PATCHD, Wp_bf, 0, 0, PATCHD, Etmp, 0, 0, HIDD,
      bp, 1, 1.0f, MPATCH, HIDD, PATCHD, 25);
  embed_merge<<<dim3(1182), 256, 0, stream>>>(Etmp, cls, pos, Z);

  for (int blk = 0; blk < NBLOCKS; ++blk) {
    // ---- LN1 ----
    ln_part<<<dim3(128), 256, 0, stream>>>(Z, stats);
    ln_apply_bf<<<dim3(1182), 256, 0, stream>>>(Z, ln1g, ln1b, stats, Xnb);

    // ---- per-column score bias D + Xnb transpose ----
    dcol<<<dim3(NBATCH * NHEADS, 4), 256, 0, stream>>>(Xnb, cvecb, Dbuf);
    xpose<<<dim3(HIDD / 64, 4, NBATCH), 256, 0, stream>>>(Xnb, Xt);

    // ---- U projection (8-phase): [1576,768] @ [9216,768]^T ----
    gemm_8ph<true><<<dim3((HH / 256) * 7, 1, 1), 512, 0, stream>>>(
        Xnb, HIDD, Mt_bf, HIDD, U, HH,
        nullptr, 1.0f, M_ALL, HH, HIDD, 7);

    // ---- scores (U @ Xnb^T + D) + fused softmax -> Pb ----
    scores_sm<<<dim3(4, 1, NBATCH * NHEADS), 256, 0, stream>>>(
        U, Xnb, Dbuf, Pb, scale);

    // ---- T = P @ Xnb (BN=128); T overwrites U ----
    gemm_bt<64, 128, 2, 2, true><<<dim3(4 * (HIDD / 128), 1, NBATCH * NHEADS), 256, 0, stream>>>(
        Pb, sPn, sPh, PLD,
        Xt, (long long)HIDD * 256, 0, 256,
        U, sUn, HIDD, HH,
        nullptr, NHEADS, 1.0f, SEQL, HIDD, KPV, 4);

    // ---- attn partials (KSPLIT=4, BN=192: A re-read 6->4): Cpart[s] = T[:,sl] @ Gcat[:,sl]^T ----
    gemm_bt<64, 192, 2, 2, false><<<dim3(25 * (HIDD / 192), 1, KSPLIT), 256, 0, stream>>>(
        U, 0, HH / KSPLIT, HH,
        Gcat, 0, HH / KSPLIT, HH,
        Cpart, 0, (long long)M_ALL * HIDD, HIDD,
        nullptr, KSPLIT, 1.0f, M_ALL, HIDD, HH / KSPLIT, 25);

    // ---- fused reduce + residual + beff + LN2 partials ----
    wo_ln_part<<<dim3(128), 256, 0, stream>>>(
        (const float4*)Cpart, (const float4*)Z, (const float4*)beff, (float4*)Ares, stats);
    ln_apply_bf<<<dim3(1182), 256, 0, stream>>>(Ares, ln2g, ln2b, stats, Xnb);

    // ---- W2 ----
    gemm_bt<64, 64, 2, 2, false><<<dim3(25 * (HIDD / 64), 1, 1), 256, 0, stream>>>(
        Xnb, 0, 0, HIDD, W2_bf, 0, 0, HIDD, Z, 0, 0, HIDD,
        b2, 1, 1.0f, M_ALL, HIDD, HIDD, 25);
  }

  // ---- head ----
  head_k<<<dim3((OUTDIM + 3) / 4), 256, 0, stream>>>(Z, Wh, bh, out);
}

// Round 25
// 1341.261 us; speedup vs baseline: 1.0379x; 1.0080x over previous
//
#include <hip/hip_runtime.h>
#include <hip/hip_bf16.h>
#include <math.h>

typedef __hip_bfloat16 bf16;
typedef __attribute__((ext_vector_type(8))) short short8;
typedef __attribute__((ext_vector_type(4))) float f32x4;

#define HIDD   768
#define SEQL   197
#define NPATCH 196
#define PATCHD 256
#define NHEADS 12
#define NBATCH 8
#define OUTDIM 1000
#define NBLOCKS 6
#define EPSV   1e-5f
#define HH     (NHEADS * HIDD)       /* 9216 */
#define M_ALL  (NBATCH * SEQL)       /* 1576 */
#define MPATCH (NBATCH * NPATCH)     /* 1568 */
#define PLD    256
#define KPV    224
#define KSPLIT 4

// ---------- helpers ----------
__device__ __forceinline__ unsigned short f2bf(float f) {
  union { bf16 h; unsigned short u; } cv; cv.h = __float2bfloat16(f); return cv.u;
}
__device__ __forceinline__ float bf2f(unsigned short u) {
  union { unsigned int i; float f; } w; w.i = ((unsigned int)u) << 16; return w.f;
}

typedef __attribute__((address_space(3))) unsigned int lds_uint;
typedef __attribute__((address_space(1))) const unsigned int g_uint;
__device__ __forceinline__ void gload16(const void* g, void* l) {
  __builtin_amdgcn_global_load_lds((g_uint*)g, (lds_uint*)l, 16, 0, 0);
}

// ---------- fp32 -> bf16 convert ----------
__global__ __launch_bounds__(256) void cvt_bf(const float4* __restrict__ src,
                                              ushort4* __restrict__ dst, int n4) {
  for (int i = blockIdx.x * 256 + threadIdx.x; i < n4; i += gridDim.x * 256) {
    float4 v = src[i];
    ushort4 o;
    o.x = f2bf(v.x); o.y = f2bf(v.y); o.z = f2bf(v.z); o.w = f2bf(v.w);
    dst[i] = o;
  }
}

// ---------- per-call: tiled fp32->bf16 per-head transpose  Dst[h][c][r] = S[h][r][c] ----------
__global__ __launch_bounds__(256) void wtrans(const float* __restrict__ S,
    unsigned short* __restrict__ Dst) {
  __shared__ unsigned short tile[64][72];
  const int h = blockIdx.z;
  const int c0 = blockIdx.x * 64, r0 = blockIdx.y * 64;
  const long long base = (long long)h * HIDD * HIDD;
  const int tr = threadIdx.x >> 2;
  const int tc = (threadIdx.x & 3) * 16;
#pragma unroll
  for (int j = 0; j < 4; ++j) {
    float4 v = *(const float4*)(S + base + (long long)(r0 + tr) * HIDD + c0 + tc + j * 4);
    tile[tr][tc + j * 4 + 0] = f2bf(v.x);
    tile[tr][tc + j * 4 + 1] = f2bf(v.y);
    tile[tr][tc + j * 4 + 2] = f2bf(v.z);
    tile[tr][tc + j * 4 + 3] = f2bf(v.w);
  }
  __syncthreads();
  const int er = threadIdx.x >> 2;
  const int ec = (threadIdx.x & 3) * 16;
  unsigned short tmp[16];
#pragma unroll
  for (int j = 0; j < 16; ++j) tmp[j] = tile[ec + j][er];
  unsigned short* drow = Dst + ((long long)h * HIDD + c0 + er) * HIDD + r0 + ec;
  *(int4*)drow = *(int4*)&tmp[0];
  *(int4*)(drow + 8) = *(int4*)&tmp[8];
}

// ---------- per-call: c[h][d'] = Wkt_bf[h][d'] . bq[h]  (wave per output) ----------
__global__ __launch_bounds__(256) void cvec2(const unsigned short* __restrict__ Wkt,
    const float* __restrict__ bq, float* __restrict__ c) {
  const int h = blockIdx.y;
  const int dp = blockIdx.x * 4 + (threadIdx.x >> 6);
  const int lane = threadIdx.x & 63;
  const unsigned short* row = Wkt + ((long long)h * HIDD + dp) * HIDD;
  const float* b = bq + h * HIDD;
  float s = 0.f;
  for (int e = lane * 4; e < HIDD; e += 256) {
    ushort4 w = *(const ushort4*)(row + e);
    s += bf2f(w.x) * b[e] + bf2f(w.y) * b[e + 1]
       + bf2f(w.z) * b[e + 2] + bf2f(w.w) * b[e + 3];
  }
  for (int o = 32; o; o >>= 1) s += __shfl_xor(s, o, 64);
  if (lane == 0) c[h * HIDD + dp] = s;
}

// ---------- one-time: beff[d] = bo[d] + Wo[d,:] . bv ----------
__global__ __launch_bounds__(256) void beff_k(const float* __restrict__ Wo,
    const float* __restrict__ bv, const float* __restrict__ bo,
    float* __restrict__ beff) {
  const int dout = blockIdx.x * 4 + (threadIdx.x >> 6);
  const int lane = threadIdx.x & 63;
  const float* row = Wo + (long long)dout * HH;
  float s = 0.f;
  for (int i = lane * 4; i < HH; i += 256) {
    float4 w = *(const float4*)(row + i);
    float4 b = *(const float4*)(bv + i);
    s += w.x * b.x + w.y * b.y + w.z * b.z + w.w * b.w;
  }
  for (int o = 32; o; o >>= 1) s += __shfl_xor(s, o, 64);
  if (lane == 0) beff[dout] = bo[dout] + s;
}

// ---------- per-iter: D[z][t] = c[h] . xnb[n*SEQL+t]  (wave per row) ----------
__global__ __launch_bounds__(256) void dcol(const unsigned short* __restrict__ Xn,
    const float* __restrict__ c, float* __restrict__ D) {
  const int z = blockIdx.x;
  const int n = z / NHEADS, h = z - n * NHEADS;
  const int wid = threadIdx.x >> 6, lane = threadIdx.x & 63;
  const float* ch = c + h * HIDD;
  float cc[3][4];
#pragma unroll
  for (int k = 0; k < 3; ++k)
    *(float4*)cc[k] = *(const float4*)(ch + k * 256 + lane * 4);
  const int t0 = blockIdx.y * 64 + wid * 16;
#pragma unroll
  for (int tt = 0; tt < 16; ++tt) {
    const int t = t0 + tt;
    float s = 0.f;
    if (t < SEQL) {
      const unsigned short* xr = Xn + (long long)(n * SEQL + t) * HIDD;
#pragma unroll
      for (int k = 0; k < 3; ++k) {
        ushort4 xv = *(const ushort4*)(xr + k * 256 + lane * 4);
        s += bf2f(xv.x) * cc[k][0] + bf2f(xv.y) * cc[k][1]
           + bf2f(xv.z) * cc[k][2] + bf2f(xv.w) * cc[k][3];
      }
    }
    for (int o = 32; o; o >>= 1) s += __shfl_xor(s, o, 64);
    if (lane == 0) D[z * 256 + t] = s;
  }
}

// ---------- per-iter: Xt[n][e][t] = Xnb[n][t][e] (ld 256, rows t>=197 zero) ----------
__global__ __launch_bounds__(256) void xpose(const unsigned short* __restrict__ Xn,
    unsigned short* __restrict__ Xt) {
  __shared__ unsigned short tile[64][72];
  const int n = blockIdx.z;
  const int e0 = blockIdx.x * 64, t0 = blockIdx.y * 64;
  const int tr = threadIdx.x >> 2;
  const int tc = (threadIdx.x & 3) * 16;
  const int t = t0 + tr;
#pragma unroll
  for (int j = 0; j < 2; ++j) {
    int4 v = {0, 0, 0, 0};
    if (t < SEQL)
      v = *(const int4*)(Xn + (long long)(n * SEQL + t) * HIDD + e0 + tc + j * 8);
    *(int4*)&tile[tr][tc + j * 8] = v;
  }
  __syncthreads();
  const int er = threadIdx.x >> 2;
  const int tcc = (threadIdx.x & 3) * 16;
  unsigned short tmp[16];
#pragma unroll
  for (int j = 0; j < 16; ++j) tmp[j] = tile[tcc + j][er];
  unsigned short* drow = Xt + ((long long)n * HIDD + e0 + er) * 256 + t0 + tcc;
  *(int4*)drow = *(int4*)&tmp[0];
  *(int4*)(drow + 8) = *(int4*)&tmp[8];
}

// =================================================================
// gemm_8ph v2 — U projection (N = 9216).
// =================================================================
template<bool BF16C>
__global__ __launch_bounds__(512, 2) void gemm_8ph(
    const unsigned short* __restrict__ A, int lda,
    const unsigned short* __restrict__ B, int ldb,
    void* __restrict__ Cp, int ldc,
    const float* __restrict__ bias, float alpha,
    int M, int N, int K, int gy)
{
  __shared__ alignas(16) unsigned short Abuf[2 * 2 * 128 * 64];
  __shared__ alignas(16) unsigned short Bbuf[2 * 2 * 128 * 64];

  const int nwg = gridDim.x;
  const int qq = nwg >> 3, rr = nwg & 7;
  const int xcd = blockIdx.x & 7, wix = blockIdx.x >> 3;
  const int f = xcd * qq + (xcd < rr ? xcd : rr) + wix;
  const int m0 = (f % gy) * 256, n0 = (f / gy) * 256;

  const int tid = threadIdx.x;
  const int lane = tid & 63, wid = tid >> 6;
  const int wr = wid >> 2, wc = wid & 3;
  const int lr = lane & 15, g = lane >> 4;

  const int srow = tid >> 3;
  const int schunk = ((tid & 7) ^ ((tid >> 3) & 7)) * 8;
  const int wbyte = wid * 1024;
  const int axor = lr & 7;

  const int ktiles = K >> 6;

  f32x4 acc[8][4];
#pragma unroll
  for (int m = 0; m < 8; ++m)
#pragma unroll
    for (int n = 0; n < 4; ++n) acc[m][n] = (f32x4){0.f, 0.f, 0.f, 0.f};

  auto stA = [&](int kt, int h) {
    const unsigned short* src = A + (long long)(m0 + h * 128 + srow) * lda + kt * 64 + schunk;
    char* dst = (char*)Abuf + ((kt & 1) * 2 + h) * 16384 + wbyte;
    gload16(src, dst);
    gload16(src + 64ll * lda, dst + 8192);
  };
  auto stB = [&](int kt, int h) {
    const unsigned short* src = B + (long long)(n0 + h * 128 + srow) * ldb + kt * 64 + schunk;
    char* dst = (char*)Bbuf + ((kt & 1) * 2 + h) * 16384 + wbyte;
    gload16(src, dst);
    gload16(src + 64ll * ldb, dst + 8192);
  };

  stB(0, 0); stB(0, 1); stA(0, 0); stA(0, 1);
  __builtin_amdgcn_s_waitcnt(0x0F72);
  __builtin_amdgcn_sched_barrier(0);
  __builtin_amdgcn_s_barrier();
  __builtin_amdgcn_sched_barrier(0);

  for (int t = 0; t < ktiles; ++t) {
    const int d = t & 1;
    const char* Ab_ = (const char*)Abuf + (d * 2 + wr) * 16384;
    const char* Bb_ = (const char*)Bbuf + (d * 2 + (wc >> 1)) * 16384;
    const int brow = (wc & 1) * 64;
    const bool more = (t + 1 < ktiles);

    short8 a[4][2], bA[2][2], bB[2][2];

    // phase 1
#pragma unroll
    for (int m = 0; m < 4; ++m)
#pragma unroll
      for (int ks = 0; ks < 2; ++ks)
        a[m][ks] = *(const short8*)(Ab_ + (m * 16 + lr) * 128 + ((((ks << 2) | g) ^ axor) << 4));
#pragma unroll
    for (int n = 0; n < 2; ++n)
#pragma unroll
      for (int ks = 0; ks < 2; ++ks)
        bA[n][ks] = *(const short8*)(Bb_ + (brow + n * 16 + lr) * 128 + ((((ks << 2) | g) ^ axor) << 4));
    if (more) stB(t + 1, 0);
    __builtin_amdgcn_sched_barrier(0);
    __builtin_amdgcn_s_barrier();
    __builtin_amdgcn_sched_barrier(0);
    __builtin_amdgcn_s_waitcnt(0xC07F);
    __builtin_amdgcn_sched_barrier(0);
    __builtin_amdgcn_s_setprio(1);
#pragma unroll
    for (int m = 0; m < 4; ++m)
#pragma unroll
      for (int n = 0; n < 2; ++n)
#pragma unroll
        for (int ks = 0; ks < 2; ++ks)
          acc[m][n] = __builtin_amdgcn_mfma_f32_16x16x32_bf16(a[m][ks], bA[n][ks], acc[m][n], 0, 0, 0);
    __builtin_amdgcn_s_setprio(0);
    __builtin_amdgcn_sched_barrier(0);
    __builtin_amdgcn_s_barrier();
    __builtin_amdgcn_sched_barrier(0);

    // phase 2
#pragma unroll
    for (int n = 0; n < 2; ++n)
#pragma unroll
      for (int ks = 0; ks < 2; ++ks)
        bB[n][ks] = *(const short8*)(Bb_ + (brow + (n + 2) * 16 + lr) * 128 + ((((ks << 2) | g) ^ axor) << 4));
    if (more) stB(t + 1, 1);
    if (more) __builtin_amdgcn_s_waitcnt(0x0F74);
    else      __builtin_amdgcn_s_waitcnt(0x0F70);
    __builtin_amdgcn_sched_barrier(0);
    __builtin_amdgcn_s_barrier();
    __builtin_amdgcn_sched_barrier(0);
    __builtin_amdgcn_s_waitcnt(0xC07F);
    __builtin_amdgcn_sched_barrier(0);
    __builtin_amdgcn_s_setprio(1);
#pragma unroll
    for (int m = 0; m < 4; ++m)
#pragma unroll
      for (int n = 0; n < 2; ++n)
#pragma unroll
        for (int ks = 0; ks < 2; ++ks)
          acc[m][n + 2] = __builtin_amdgcn_mfma_f32_16x16x32_bf16(a[m][ks], bB[n][ks], acc[m][n + 2], 0, 0, 0);
    __builtin_amdgcn_s_setprio(0);
    __builtin_amdgcn_sched_barrier(0);
    __builtin_amdgcn_s_barrier();
    __builtin_amdgcn_sched_barrier(0);

    // phase 3
#pragma unroll
    for (int m = 0; m < 4; ++m)
#pragma unroll
      for (int ks = 0; ks < 2; ++ks)
        a[m][ks] = *(const short8*)(Ab_ + (64 + m * 16 + lr) * 128 + ((((ks << 2) | g) ^ axor) << 4));
    if (more) stA(t + 1, 0);
    __builtin_amdgcn_sched_barrier(0);
    __builtin_amdgcn_s_barrier();
    __builtin_amdgcn_sched_barrier(0);
    __builtin_amdgcn_s_waitcnt(0xC07F);
    __builtin_amdgcn_sched_barrier(0);
    __builtin_amdgcn_s_setprio(1);
#pragma unroll
    for (int m = 0; m < 4; ++m)
#pragma unroll
      for (int n = 0; n < 2; ++n)
#pragma unroll
        for (int ks = 0; ks < 2; ++ks)
          acc[m + 4][n + 2] = __builtin_amdgcn_mfma_f32_16x16x32_bf16(a[m][ks], bB[n][ks], acc[m + 4][n + 2], 0, 0, 0);
    __builtin_amdgcn_s_setprio(0);
    __builtin_amdgcn_sched_barrier(0);
    __builtin_amdgcn_s_barrier();
    __builtin_amdgcn_sched_barrier(0);

    // phase 4
    if (more) {
      stA(t + 1, 1);
      __builtin_amdgcn_s_waitcnt(0x0F72);
    }
    __builtin_amdgcn_sched_barrier(0);
    __builtin_amdgcn_s_barrier();
    __builtin_amdgcn_sched_barrier(0);
    __builtin_amdgcn_s_setprio(1);
#pragma unroll
    for (int m = 0; m < 4; ++m)
#pragma unroll
      for (int n = 0; n < 2; ++n)
#pragma unroll
        for (int ks = 0; ks < 2; ++ks)
          acc[m + 4][n] = __builtin_amdgcn_mfma_f32_16x16x32_bf16(a[m][ks], bA[n][ks], acc[m + 4][n], 0, 0, 0);
    __builtin_amdgcn_s_setprio(0);
    __builtin_amdgcn_sched_barrier(0);
    __builtin_amdgcn_s_barrier();
    __builtin_amdgcn_sched_barrier(0);
  }

#pragma unroll
  for (int m = 0; m < 8; ++m) {
#pragma unroll
    for (int n = 0; n < 4; ++n) {
      const int gn = n0 + wc * 64 + n * 16 + lr;
      const float bv = bias ? bias[gn] : 0.f;
#pragma unroll
      for (int r = 0; r < 4; ++r) {
        const int gm = m0 + wr * 128 + m * 16 + g * 4 + r;
        if (gm >= M) continue;
        const float v = acc[m][n][r] * alpha + bv;
        if constexpr (BF16C)
          ((unsigned short*)Cp)[(long long)gm * ldc + gn] = f2bf(v);
        else
          ((float*)Cp)[(long long)gm * ldc + gn] = v;
      }
    }
  }
}

// =================================================================
// gemm_bt: 2-phase pipeline — T / G-attn / W2 / patch-embed / Mt / G prep
// (256,4): allow 4 blocks/CU (36KB LDS) — eliminates the 600-block tail.
// =================================================================
template<int BM, int BN, int WGM, int WGN, bool BF16C>
__global__ __launch_bounds__(256, 4) void gemm_bt(
    const unsigned short* __restrict__ A, long long sAz1, long long sAz2, int lda,
    const unsigned short* __restrict__ B, long long sBz1, long long sBz2, int ldb,
    void* __restrict__ Cp, long long sCz1, long long sCz2, int ldc,
    const float* __restrict__ bias, int zdiv, float alpha,
    int M, int N, int K, int gy)
{
  constexpr int BK = 32;
  constexpr int VM = BM / 64 + BN / 64;
  static_assert(WGM * WGN == 4, "4 waves");
  __shared__ unsigned short As[3][BM * BK];
  __shared__ unsigned short Bs[3][BN * BK];

  const int z  = blockIdx.z;
  const int z1 = z / zdiv, z2 = z - z1 * zdiv;
  const unsigned short* Ab = A + z1 * sAz1 + z2 * sAz2;
  const unsigned short* Bb = B + z1 * sBz1 + z2 * sBz2;
  const long long coff = z1 * sCz1 + z2 * sCz2;

  const int nwg = gridDim.x;
  const int qq = nwg >> 3, rr = nwg & 7;
  const int xcd = blockIdx.x & 7, wix = blockIdx.x >> 3;
  const int f = xcd * qq + (xcd < rr ? xcd : rr) + wix;
  const int m0 = (f % gy) * BM, n0 = (f / gy) * BN;

  const int tid = threadIdx.x;
  const int lane = tid & 63, wid = tid >> 6;
  const int wr = wid / WGN, wc = wid % WGN;
  constexpr int WM = BM / WGM, WN = BN / WGN, TM = WM / 16, TN = WN / 16;
  const int lr = lane & 15, g = lane >> 4;

  const int sr = wid * 16 + (lane >> 2);
  const int sc = (((lane & 3) ^ ((lane >> 3) & 3)) * 8);
  const int wbyte = wid * 1024;

  f32x4 acc[TM][TN];
#pragma unroll
  for (int m = 0; m < TM; ++m)
#pragma unroll
    for (int n = 0; n < TN; ++n) acc[m][n] = (f32x4){0.f, 0.f, 0.f, 0.f};

  auto stage = [&](int bufi, int kt) {
    const int k0 = kt * BK;
#pragma unroll
    for (int u = 0; u < BM / 64; ++u)
      gload16(Ab + (long long)(m0 + u * 64 + sr) * lda + k0 + sc,
              (char*)&As[bufi][0] + u * 4096 + wbyte);
#pragma unroll
    for (int u = 0; u < BN / 64; ++u)
      gload16(Bb + (long long)(n0 + u * 64 + sr) * ldb + k0 + sc,
              (char*)&Bs[bufi][0] + u * 4096 + wbyte);
  };

  const int rchunk = (g ^ ((lr >> 1) & 3)) * 8;

  const int ktiles = K / BK;
  stage(0, 0);
  if (ktiles > 1) stage(1, 1);
  int cur = 0;
  for (int t = 0; t < ktiles; ++t) {
    if (t + 1 < ktiles) __builtin_amdgcn_s_waitcnt(0x0F70 | VM);
    else                __builtin_amdgcn_s_waitcnt(0x0F70);
    __builtin_amdgcn_s_barrier();
    if (t + 2 < ktiles) {
      int nb = cur + 2; if (nb >= 3) nb -= 3;
      stage(nb, t + 2);
    }
    __builtin_amdgcn_sched_barrier(0);

    short8 a[TM], b[TN];
#pragma unroll
    for (int m = 0; m < TM; ++m)
      a[m] = *(const short8*)&As[cur][(wr * WM + m * 16 + lr) * BK + rchunk];
#pragma unroll
    for (int n = 0; n < TN; ++n)
      b[n] = *(const short8*)&Bs[cur][(wc * WN + n * 16 + lr) * BK + rchunk];
#pragma unroll
    for (int m = 0; m < TM; ++m)
#pragma unroll
      for (int n = 0; n < TN; ++n)
        acc[m][n] = __builtin_amdgcn_mfma_f32_16x16x32_bf16(a[m], b[n], acc[m][n], 0, 0, 0);
    cur = (cur == 2) ? 0 : cur + 1;
  }

#pragma unroll
  for (int m = 0; m < TM; ++m) {
#pragma unroll
    for (int n = 0; n < TN; ++n) {
      const int gn = n0 + wc * WN + n * 16 + lr;
      if (gn >= N) continue;
      const float bv = bias ? bias[gn] : 0.f;
#pragma unroll
      for (int r = 0; r < 4; ++r) {
        const int gm = m0 + wr * WM + m * 16 + g * 4 + r;
        if (gm >= M) continue;
        const float v = acc[m][n][r] * alpha + bv;
        if constexpr (BF16C)
          ((unsigned short*)Cp)[coff + (long long)gm * ldc + gn] = f2bf(v);
        else
          ((float*)Cp)[coff + (long long)gm * ldc + gn] = v;
      }
    }
  }
}

// =================================================================
// scores_sm: per z=(n,h), S = scale * (U[h] @ Xnb^T + D) with fused softmax.
// =================================================================
__global__ __launch_bounds__(256, 2) void scores_sm(
    const unsigned short* __restrict__ U, const unsigned short* __restrict__ Xn,
    const float* __restrict__ Dv, unsigned short* __restrict__ P, float scale)
{
  constexpr int BK = 32;
  __shared__ unsigned short As[3][64 * BK];
  __shared__ unsigned short Bs[3][256 * BK];

  const int z  = blockIdx.z;
  const int z1 = z / NHEADS, z2 = z - z1 * NHEADS;
  const unsigned short* Ab = U + (long long)z1 * SEQL * HH + (long long)z2 * HIDD;
  const unsigned short* Bb = Xn + (long long)z1 * SEQL * HIDD;
  unsigned short* Pz = P + (long long)z * SEQL * PLD;

  const int m0 = blockIdx.x * 64;
  const int tid = threadIdx.x;
  const int lane = tid & 63, wid = tid >> 6;
  const int lr = lane & 15, g = lane >> 4;

  const int sr = wid * 16 + (lane >> 2);
  const int sc = (((lane & 3) ^ ((lane >> 3) & 3)) * 8);
  const int wbyte = wid * 1024;
  const int rchunk = (g ^ ((lr >> 1) & 3)) * 8;

  f32x4 acc[16];
#pragma unroll
  for (int n = 0; n < 16; ++n) acc[n] = (f32x4){0.f, 0.f, 0.f, 0.f};

  auto stage = [&](int bufi, int kt) {
    const int k0 = kt * BK;
    gload16(Ab + (long long)(m0 + sr) * HH + k0 + sc, (char*)&As[bufi][0] + wbyte);
#pragma unroll
    for (int u = 0; u < 4; ++u)
      gload16(Bb + (long long)(u * 64 + sr) * HIDD + k0 + sc,
              (char*)&Bs[bufi][0] + u * 4096 + wbyte);
  };

  const int ktiles = HIDD / BK;
  stage(0, 0);
  stage(1, 1);
  int cur = 0;
  for (int t = 0; t < ktiles; ++t) {
    if (t + 1 < ktiles) __builtin_amdgcn_s_waitcnt(0x0F75);
    else                __builtin_amdgcn_s_waitcnt(0x0F70);
    __builtin_amdgcn_s_barrier();
    if (t + 2 < ktiles) {
      int nb = cur + 2; if (nb >= 3) nb -= 3;
      stage(nb, t + 2);
    }
    __builtin_amdgcn_sched_barrier(0);

    short8 a = *(const short8*)&As[cur][(wid * 16 + lr) * BK + rchunk];
#pragma unroll
    for (int n = 0; n < 16; ++n) {
      short8 b = *(const short8*)&Bs[cur][(n * 16 + lr) * BK + rchunk];
      acc[n] = __builtin_amdgcn_mfma_f32_16x16x32_bf16(a, b, acc[n], 0, 0, 0);
    }
    cur = (cur == 2) ? 0 : cur + 1;
  }

  const float* Dz = Dv + z * 256;
  float dv[16];
#pragma unroll
  for (int n = 0; n < 16; ++n) dv[n] = Dz[n * 16 + lr];

  const int growb = m0 + wid * 16 + g * 4;
#pragma unroll
  for (int r = 0; r < 4; ++r) {
    float mx = -1e30f;
#pragma unroll
    for (int n = 0; n < 16; ++n)
      if (n * 16 + lr < SEQL) mx = fmaxf(mx, (acc[n][r] + dv[n]) * scale);
    for (int o = 1; o < 16; o <<= 1) mx = fmaxf(mx, __shfl_xor(mx, o, 64));
    float sum = 0.f;
#pragma unroll
    for (int n = 0; n < 16; ++n) {
      const float e = (n * 16 + lr < SEQL) ? __expf((acc[n][r] + dv[n]) * scale - mx) : 0.f;
      acc[n][r] = e;
      sum += e;
    }
    for (int o = 1; o < 16; o <<= 1) sum += __shfl_xor(sum, o, 64);
    const float inv = 1.f / sum;
    const int grow = growb + r;
    if (grow < SEQL) {
#pragma unroll
      for (int n = 0; n < 16; ++n)
        Pz[(long long)grow * PLD + n * 16 + lr] = f2bf(acc[n][r] * inv);
    }
  }
}

// =================================================================
// head_k: out[n][o] = tanh(Z[n,0,:] . Wh[o,:] + bh[o])
// =================================================================
__global__ __launch_bounds__(256) void head_k(
    const float* __restrict__ Z, const float* __restrict__ Wh,
    const float* __restrict__ bh, float* __restrict__ out)
{
  __shared__ float Zs[NBATCH][HIDD];
  for (int i = threadIdx.x; i < NBATCH * (HIDD / 4); i += 256) {
    const int n = i / (HIDD / 4);
    const int k4 = i - n * (HIDD / 4);
    float4 v = *(const float4*)(Z + (long long)n * SEQL * HIDD + k4 * 4);
    *(float4*)&Zs[n][k4 * 4] = v;
  }
  __syncthreads();

  const int wid = threadIdx.x >> 6, lane = threadIdx.x & 63;
  const int o = blockIdx.x * 4 + wid;
  if (o >= OUTDIM) return;
  const float* wrow = Wh + (long long)o * HIDD;
  float s[NBATCH];
#pragma unroll
  for (int n = 0; n < NBATCH; ++n) s[n] = 0.f;
  for (int k = lane * 4; k < HIDD; k += 256) {
    float4 w = *(const float4*)(wrow + k);
#pragma unroll
    for (int n = 0; n < NBATCH; ++n) {
      float4 zv = *(const float4*)&Zs[n][k];
      s[n] += w.x * zv.x + w.y * zv.y + w.z * zv.z + w.w * zv.w;
    }
  }
#pragma unroll
  for (int n = 0; n < NBATCH; ++n)
    for (int off2 = 32; off2; off2 >>= 1) s[n] += __shfl_xor(s[n], off2, 64);
  if (lane == 0) {
    const float b = bh[o];
#pragma unroll
    for (int n = 0; n < NBATCH; ++n)
      out[n * OUTDIM + o] = tanhf(s[n] + b);
  }
}

// ---------- embed merge ----------
__global__ __launch_bounds__(256) void embed_merge(
    const float* __restrict__ Etmp, const float* __restrict__ cls,
    const float* __restrict__ pos, float* __restrict__ Z)
{
  const int tot = NBATCH * SEQL * HIDD / 4;
  for (int i = blockIdx.x * 256 + threadIdx.x; i < tot; i += gridDim.x * 256) {
    const int n  = i / (SEQL * HIDD / 4);
    const int se = i - n * (SEQL * HIDD / 4);
    const int s  = se / (HIDD / 4);
    const int e4 = se - s * (HIDD / 4);
    float4 pv = ((const float4*)pos)[se];
    float4 src;
    if (s == 0) src = ((const float4*)cls)[e4];
    else        src = ((const float4*)Etmp)[(long long)(n * NPATCH + s - 1) * (HIDD / 4) + e4];
    float4 o;
    o.x = src.x + pv.x; o.y = src.y + pv.y;
    o.z = src.z + pv.z; o.w = src.w + pv.w;
    ((float4*)Z)[i] = o;
  }
}

// ---------- LN partial pass ----------
__global__ __launch_bounds__(256) void ln_part(const float* __restrict__ x, float* __restrict__ part) {
  const int b = blockIdx.x;
  const int n = b >> 4, seg = b & 15;
  const int per = (SEQL * HIDD / 4) / 16;
  const float4* px = (const float4*)(x + (size_t)n * SEQL * HIDD);
  float s = 0.f, q = 0.f;
  for (int i = seg * per + threadIdx.x; i < (seg + 1) * per; i += 256) {
    float4 v = px[i];
    s += v.x + v.y + v.z + v.w;
    q += v.x * v.x + v.y * v.y + v.z * v.z + v.w * v.w;
  }
  for (int o = 32; o; o >>= 1) { s += __shfl_xor(s, o, 64); q += __shfl_xor(q, o, 64); }
  __shared__ float ls[8];
  const int wid = threadIdx.x >> 6, lane = threadIdx.x & 63;
  if (lane == 0) { ls[wid] = s; ls[4 + wid] = q; }
  __syncthreads();
  if (threadIdx.x == 0) {
    part[b] = ls[0] + ls[1] + ls[2] + ls[3];
    part[128 + b] = ls[4] + ls[5] + ls[6] + ls[7];
  }
}

// ---------- fused reduce (KSPLIT) + residual(beff) + LN2 partials ----------
__global__ __launch_bounds__(256) void wo_ln_part(
    const float4* __restrict__ Cp, const float4* __restrict__ Z4,
    const float4* __restrict__ bo4, float4* __restrict__ out4,
    float* __restrict__ part)
{
  const int b = blockIdx.x;
  const int n = b >> 4, seg = b & 15;
  const int per = (SEQL * HIDD / 4) / 16;
  const int tot = M_ALL * HIDD / 4;
  const long long base = (long long)n * (SEQL * HIDD / 4);
  float s = 0.f, q = 0.f;
  for (int i = seg * per + threadIdx.x; i < (seg + 1) * per; i += 256) {
    const long long gi = base + i;
    float4 zv = Z4[gi];
    float4 bb = bo4[i % (HIDD / 4)];
    float4 o;
    o.x = zv.x + bb.x; o.y = zv.y + bb.y;
    o.z = zv.z + bb.z; o.w = zv.w + bb.w;
#pragma unroll
    for (int sp = 0; sp < KSPLIT; ++sp) {
      float4 c = Cp[(long long)sp * tot + gi];
      o.x += c.x; o.y += c.y; o.z += c.z; o.w += c.w;
    }
    out4[gi] = o;
    s += o.x + o.y + o.z + o.w;
    q += o.x * o.x + o.y * o.y + o.z * o.z + o.w * o.w;
  }
  for (int o = 32; o; o >>= 1) { s += __shfl_xor(s, o, 64); q += __shfl_xor(q, o, 64); }
  __shared__ float ls[8];
  const int wid = threadIdx.x >> 6, lane = threadIdx.x & 63;
  if (lane == 0) { ls[wid] = s; ls[4 + wid] = q; }
  __syncthreads();
  if (threadIdx.x == 0) {
    part[b] = ls[0] + ls[1] + ls[2] + ls[3];
    part[128 + b] = ls[4] + ls[5] + ls[6] + ls[7];
  }
}

// ---------- LN apply -> bf16 ----------
__global__ __launch_bounds__(256) void ln_apply_bf(const float* __restrict__ x,
    const float* __restrict__ g, const float* __restrict__ b,
    const float* __restrict__ part, unsigned short* __restrict__ y)
{
  __shared__ float ms[8], rs[8];
  if (threadIdx.x < 8) {
    const int n = threadIdx.x;
    float s = 0.f, qv = 0.f;
    for (int j = 0; j < 16; ++j) { s += part[n * 16 + j]; qv += part[128 + n * 16 + j]; }
    const float inv = 1.f / (float)(SEQL * HIDD);
    const float m = s * inv;
    ms[n] = m;
    rs[n] = rsqrtf(qv * inv - m * m + EPSV);
  }
  __syncthreads();
  const int tot = NBATCH * SEQL * HIDD / 4;
  for (int i = blockIdx.x * 256 + threadIdx.x; i < tot; i += gridDim.x * 256) {
    const int n  = i / (SEQL * HIDD / 4);
    const int se = i - n * (SEQL * HIDD / 4);
    const float m = ms[n], r = rs[n];
    float4 xv = ((const float4*)x)[i];
    float4 gv = ((const float4*)g)[se];
    float4 bv = ((const float4*)b)[se];
    ushort4 o;
    o.x = f2bf((xv.x - m) * r * gv.x + bv.x);
    o.y = f2bf((xv.y - m) * r * gv.y + bv.y);
    o.z = f2bf((xv.z - m) * r * gv.z + bv.z);
    o.w = f2bf((xv.w - m) * r * gv.w + bv.w);
    ((ushort4*)y)[i] = o;
  }
}

// ---------------------------------------------------------------
extern "C" void kernel_launch(void* const* d_in, const int* in_sizes, int n_in,
                              void* d_out, int out_size, void* d_ws, size_t ws_size,
                              hipStream_t stream)
{
  const float* X    = (const float*)d_in[0];
  const float* Wp   = (const float*)d_in[1];
  const float* bp   = (const float*)d_in[2];
  const float* cls  = (const float*)d_in[3];
  const float* pos  = (const float*)d_in[4];
  const float* ln1g = (const float*)d_in[5];
  const float* ln1b = (const float*)d_in[6];
  const float* Wq   = (const float*)d_in[7];
  const float* bq   = (const float*)d_in[8];
  const float* Wk   = (const float*)d_in[9];
  const float* bk   = (const float*)d_in[10];
  const float* Wv   = (const float*)d_in[11];
  const float* bv   = (const float*)d_in[12];
  const float* Wo   = (const float*)d_in[13];
  const float* bo   = (const float*)d_in[14];
  const float* ln2g = (const float*)d_in[15];
  const float* ln2b = (const float*)d_in[16];
  const float* W2   = (const float*)d_in[17];
  const float* b2   = (const float*)d_in[18];
  const float* Wh   = (const float*)d_in[19];
  const float* bh   = (const float*)d_in[20];
  float* out = (float*)d_out;
  (void)in_sizes; (void)n_in; (void)out_size; (void)ws_size;

  char* base = (char*)d_ws;
  size_t off = 0;
  auto alloc = [&](size_t bytes) -> char* {
    char* r = base + off;
    off += (bytes + 255) & ~(size_t)255;
    return r;
  };
  const size_t ZB  = (size_t)M_ALL * HIDD * 4;
  const size_t XB  = (size_t)M_ALL * HIDD * 2;
  const size_t DB  = (size_t)NBATCH * NHEADS * 256 * 4;
  const size_t PB  = (size_t)NBATCH * NHEADS * SEQL * PLD * 2;
  const size_t XTB = (size_t)NBATCH * HIDD * 256 * 2;
  const size_t UB  = (size_t)M_ALL * HH * 2;
  const size_t MTB = (size_t)HH * HIDD * 2;
  const size_t CPB = (size_t)KSPLIT * M_ALL * HIDD * 4;

  float*          Z     = (float*)alloc(ZB);
  float*          Ares  = (float*)alloc(ZB);
  unsigned short* Xnb   = (unsigned short*)alloc(XB);
  float*          stats = (float*)alloc(4096);
  float*          Dbuf  = (float*)alloc(DB);
  unsigned short* Pb    = (unsigned short*)alloc(PB);
  unsigned short* Xt    = (unsigned short*)alloc(XTB);
  unsigned short* U     = (unsigned short*)alloc(UB);
  unsigned short* Mt_bf = (unsigned short*)alloc(MTB);
  unsigned short* Gcat  = (unsigned short*)alloc(MTB);
  unsigned short* W2_bf = (unsigned short*)alloc((size_t)HIDD * HIDD * 2);
  float*          cvecb = (float*)alloc((size_t)NHEADS * HIDD * 4);
  float*          beff  = (float*)alloc((size_t)HIDD * 4);
  float*          Cpart = (float*)alloc(CPB);

  // per-call prep scratch aliases:
  unsigned short* Wkt   = U;
  unsigned short* Wqt   = U + (size_t)NHEADS * HIDD * HIDD;
  unsigned short* Wvt   = (unsigned short*)Cpart;
  unsigned short* Wo_bf = (unsigned short*)base;
  unsigned short* Xbf   = Pb;
  unsigned short* Wp_bf = Pb + 425984;
  float*          Etmp  = Cpart;

  const float scale = 1.0f / ((float)HIDD * (float)HIDD);
  const long long sUn = (long long)SEQL * HH;
  const long long sPn = (long long)NHEADS * SEQL * PLD;
  const long long sPh = (long long)SEQL * PLD;
  const long long HH2 = (long long)HIDD * HIDD;
  const int W24 = HIDD * HIDD / 4;

  // ---- per-call weight prep ----
  wtrans<<<dim3(12, 12, NHEADS), 256, 0, stream>>>(Wk, Wkt);
  wtrans<<<dim3(12, 12, NHEADS), 256, 0, stream>>>(Wq, Wqt);
  wtrans<<<dim3(12, 12, NHEADS), 256, 0, stream>>>(Wv, Wvt);
  gemm_bt<64, 64, 2, 2, true><<<dim3(144, 1, NHEADS), 256, 0, stream>>>(
      Wkt, 0, HH2, HIDD,
      Wqt, 0, HH2, HIDD,
      Mt_bf, 0, HH2, HIDD,
      nullptr, NHEADS, 1.0f, HIDD, HIDD, HIDD, 12);
  cvec2<<<dim3(HIDD / 4, NHEADS), 256, 0, stream>>>(Wkt, bq, cvecb);
  cvt_bf<<<dim3(4096), 256, 0, stream>>>((const float4*)Wo, (ushort4*)Wo_bf, HH * HIDD / 4);
  gemm_bt<64, 64, 2, 2, true><<<dim3(144, 1, NHEADS), 256, 0, stream>>>(
      Wo_bf, 0, HIDD, HH,
      Wvt, 0, HH2, HIDD,
      Gcat, 0, HIDD, HH,
      nullptr, NHEADS, 1.0f, HIDD, HIDD, HIDD, 12);
  beff_k<<<dim3(HIDD / 4), 256, 0, stream>>>(Wo, bv, bo, beff);
  cvt_bf<<<dim3(512), 256, 0, stream>>>((const float4*)W2, (ushort4*)W2_bf, W24);
  cvt_bf<<<dim3(392), 256, 0, stream>>>((const float4*)X,  (ushort4*)Xbf,  MPATCH * PATCHD / 4);
  cvt_bf<<<dim3(192), 256, 0, stream>>>((const float4*)Wp, (ushort4*)Wp_bf, HIDD * PATCHD / 4);
  gemm_bt<64, 64, 2, 2, false><<<dim3(25 * (HIDD / 64), 1, 1), 256, 0, stream>>>(
      Xbf, 0, 0, PATCHD, Wp_bf, 0, 0, PATCHD, Etmp, 0, 0, HIDD,
      bp, 1, 1.0f, MPATCH, HIDD, PATCHD, 25);
  embed_merge<<<dim3(1182), 256, 0, stream>>>(Etmp, cls, pos, Z);

  for (int blk = 0; blk < NBLOCKS; ++blk) {
    // ---- LN1 ----
    ln_part<<<dim3(128), 256, 0, stream>>>(Z, stats);
    ln_apply_bf<<<dim3(1182), 256, 0, stream>>>(Z, ln1g, ln1b, stats, Xnb);

    // ---- per-column score bias D + Xnb transpose ----
    dcol<<<dim3(NBATCH * NHEADS, 4), 256, 0, stream>>>(Xnb, cvecb, Dbuf);
    xpose<<<dim3(HIDD / 64, 4, NBATCH), 256, 0, stream>>>(Xnb, Xt);

    // ---- U projection (8-phase): [1576,768] @ [9216,768]^T ----
    gemm_8ph<true><<<dim3((HH / 256) * 7, 1, 1), 512, 0, stream>>>(
        Xnb, HIDD, Mt_bf, HIDD, U, HH,
        nullptr, 1.0f, M_ALL, HH, HIDD, 7);

    // ---- scores (U @ Xnb^T + D) + fused softmax -> Pb ----
    scores_sm<<<dim3(4, 1, NBATCH * NHEADS), 256, 0, stream>>>(
        U, Xnb, Dbuf, Pb, scale);

    // ---- T = P @ Xnb (BN=128); T overwrites U ----
    gemm_bt<64, 128, 2, 2, true><<<dim3(4 * (HIDD / 128), 1, NBATCH * NHEADS), 256, 0, stream>>>(
        Pb, sPn, sPh, PLD,
        Xt, (long long)HIDD * 256, 0, 256,
        U, sUn, HIDD, HH,
        nullptr, NHEADS, 1.0f, SEQL, HIDD, KPV, 4);

    // ---- attn partials (KSPLIT=4, BN=128, 4 blk/CU): Cpart[s] = T[:,sl] @ Gcat[:,sl]^T ----
    gemm_bt<64, 128, 2, 2, false><<<dim3(25 * (HIDD / 128), 1, KSPLIT), 256, 0, stream>>>(
        U, 0, HH / KSPLIT, HH,
        Gcat, 0, HH / KSPLIT, HH,
        Cpart, 0, (long long)M_ALL * HIDD, HIDD,
        nullptr, KSPLIT, 1.0f, M_ALL, HIDD, HH / KSPLIT, 25);

    // ---- fused reduce + residual + beff + LN2 partials ----
    wo_ln_part<<<dim3(128), 256, 0, stream>>>(
        (const float4*)Cpart, (const float4*)Z, (const float4*)beff, (float4*)Ares, stats);
    ln_apply_bf<<<dim3(1182), 256, 0, stream>>>(Ares, ln2g, ln2b, stats, Xnb);

    // ---- W2 ----
    gemm_bt<64, 64, 2, 2, false><<<dim3(25 * (HIDD / 64), 1, 1), 256, 0, stream>>>(
        Xnb, 0, 0, HIDD, W2_bf, 0, 0, HIDD, Z, 0, 0, HIDD,
        b2, 1, 1.0f, M_ALL, HIDD, HIDD, 25);
  }

  // ---- head ----
  head_k<<<dim3((OUTDIM + 3) / 4), 256, 0, stream>>>(Z, Wh, bh, out);
}